// Round 10
// baseline (495.998 us; speedup 1.0000x reference)
//
#include <hip/hip_runtime.h>
#include <math.h>

#define Bn 16
#define Tn 384
#define Cn 128

// ---------------- workspace layout (floats) ----------------
static constexpr long OFF_XT   = 0;         // 786432
static constexpr long OFF_AVG  = 786432;    // 49152 (channel-major: [c][t])
static constexpr long OFF_PER  = 835584;    // 256 ints
static constexpr long OFF_MP   = 835840;    // 1671300
static constexpr long OFF_AT   = 2507140;   // 98304
static constexpr long OFF_WAF  = 2605444;   // 589824
static constexpr long OFF_QAT  = 3195268;   // 196608
static constexpr long OFF_VAT  = 3391876;   // 196608
static constexpr long OFF_OVT  = 3588484;   // 786432
static constexpr long OFF_CON  = 4374916;   // 3072
static constexpr long OFF_VB   = 4377988;   // 1024
static constexpr long OFF_MT   = 4379012;   // 294912
static constexpr long OFF_DEF  = 4673924;   // 3080
static constexpr long OFF_ZC   = 4677004;   // 1966080
static constexpr long OFF_COMB = 6643084;   // 3145728
static constexpr long OFF_H    = 9788812;   // 1048576
static constexpr long OFF_H2   = 10837388;  // 1048576
static constexpr long WS_FLOATS = 11885964; // ~47.5 MB

__host__ __device__ inline int nanch(int p) {
  if (p == 384) return 96;
  return (p <= 18) ? 12 : (p <= 36) ? 24 : (p <= 72) ? 48 : 96;
}
__host__ __device__ inline int apre(int n) {
  return (n == 12) ? 0 : (n == 24) ? 12 : (n == 48) ? 36 : 84;
}
__host__ __device__ inline long mpoff(int p) {
  if (p == 384) return 1634436L;
  long T = (long)(p - 1) * p / 2;
  if (p <= 18) return 12 * (T - 6);
  if (p <= 36) return 1980 + 24 * (T - 171);
  if (p <= 72) return 13860 + 48 * (T - 666);
  return 108036 + 96 * (T - 2628);
}

__device__ inline void irow(int j, int newl, int oldl, int& i0, int& i1, float& w) {
  double src = ((double)j + 0.5) * (double)oldl / (double)newl - 0.5;
  if (src < 0.0) src = 0.0;
  double mx = (double)(oldl - 1);
  if (src > mx) src = mx;
  int a = (int)src;
  if (a > oldl - 1) a = oldl - 1;
  i0 = a;
  i1 = (a + 1 < oldl) ? (a + 1) : (oldl - 1);
  w = (float)(src - (double)a);
}

// ---------------- stage 0: transpose x -> xT[c][b][t] ----------------
__global__ __launch_bounds__(256) void transpose_kernel(const float* __restrict__ x,
                                                        float* __restrict__ xT) {
  __shared__ float tile[32 * 129];
  int bid = blockIdx.x;
  int b = bid / 12, t0 = (bid % 12) * 32;
  int tid = threadIdx.x;
  for (int i = tid; i < 32 * 128; i += 256) {
    int tt = i >> 7, cc = i & 127;
    tile[tt * 129 + cc] = x[((long)b * Tn + t0 + tt) * Cn + cc];
  }
  __syncthreads();
  for (int i = tid; i < 32 * 128; i += 256) {
    int cc = i >> 5, tt = i & 31;
    xT[((long)cc * Bn + b) * Tn + t0 + tt] = tile[tt * 129 + cc];
  }
}

// ---------------- stage A1: ACF (writes avg[c][t]) ----------------
__global__ __launch_bounds__(256) void acf_kernel(const float* __restrict__ xT,
                                                  float* __restrict__ avg) {
  __shared__ float xb[Bn * 397];
  __shared__ float mean[Bn];
  int bid = blockIdx.x;
  int c = bid / 6, tile = bid % 6;
  int tid = threadIdx.x;
  for (int i = tid; i < Bn * Tn; i += 256) {
    int b = i / Tn, t = i - b * Tn;
    xb[b * 397 + t] = xT[(long)c * Bn * Tn + i];
  }
  for (int i = tid; i < Bn * 13; i += 256) {
    int b = i / 13, t = Tn + (i - b * 13);
    xb[b * 397 + t] = 0.f;
  }
  __syncthreads();
  if (tid < Bn) {
    float s = 0.f;
    for (int t = 0; t < Tn; ++t) s += xb[tid * 397 + t];
    mean[tid] = s / (float)Tn;
  }
  __syncthreads();
  for (int i = tid; i < Bn * Tn; i += 256) {
    int b = i / Tn, t = i - b * Tn;
    xb[b * 397 + t] -= mean[b];
  }
  __syncthreads();
  int q = tid >> 4;
  int g = tid & 15;
  int tau0 = tile * 64 + q * 4;
  const float* xr = xb + g * 397;
  float a0 = 0.f, a1 = 0.f, a2 = 0.f, a3 = 0.f;
  float w0 = xr[tau0], w1 = xr[tau0 + 1], w2 = xr[tau0 + 2], w3 = xr[tau0 + 3];
  int tmax = Tn - tau0;
  for (int t = 0; t < tmax; ++t) {
    float a = xr[t];
    float wn = xr[t + tau0 + 4];
    a0 += a * w0; a1 += a * w1; a2 += a * w2; a3 += a * w3;
    w0 = w1; w1 = w2; w2 = w3; w3 = wn;
  }
  for (int off = 8; off > 0; off >>= 1) {
    a0 += __shfl_down(a0, off, 16);
    a1 += __shfl_down(a1, off, 16);
    a2 += __shfl_down(a2, off, 16);
    a3 += __shfl_down(a3, off, 16);
  }
  if (g == 0) {
    float* dst = avg + (long)c * Tn + tau0;
    dst[0] = a0; dst[1] = a1; dst[2] = a2; dst[3] = a3;
  }
}

// ---------------- stage A2: peaks ----------------
__global__ __launch_bounds__(256) void periods_kernel(const float* __restrict__ avg,
                                                      int* __restrict__ per) {
  int wv = threadIdx.x >> 6;
  int lane = threadIdx.x & 63;
  int c = blockIdx.x * 4 + wv;
  const float* a = avg + (long)c * Tn;
  const float NEG = -1e30f;
  float b1v = NEG, b2v = NEG;
  int b1i = 0, b2i = 0;
  int t0 = 4 + lane * 6;
#pragma unroll
  for (int i = 0; i < 6; ++i) {
    int t = t0 + i;
    if (t > Tn - 1) break;
    float v = a[t];
    float pv = (t == 4) ? NEG : a[t - 1];
    float nv = (t == Tn - 1) ? NEG : a[t + 1];
    bool peak = (v > pv) && (v > nv) && (v > 0.f);
    float m = peak ? v : NEG;
    if (m > b1v || (m == b1v && t < b1i)) {
      b2v = b1v; b2i = b1i; b1v = m; b1i = t;
    } else if (m > b2v || (m == b2v && t < b2i)) {
      b2v = m; b2i = t;
    }
  }
  for (int off = 32; off > 0; off >>= 1) {
    float c1v = __shfl_down(b1v, off, 64); int c1i = __shfl_down(b1i, off, 64);
    float c2v = __shfl_down(b2v, off, 64); int c2i = __shfl_down(b2i, off, 64);
    if (c1v > b1v || (c1v == b1v && c1i < b1i)) {
      b2v = b1v; b2i = b1i; b1v = c1v; b1i = c1i;
    } else if (c1v > b2v || (c1v == b2v && c1i < b2i)) {
      b2v = c1v; b2i = c1i;
    }
    if (c2v > b1v || (c2v == b1v && c2i < b1i)) {
      b2v = b1v; b2i = b1i; b1v = c2v; b1i = c2i;
    } else if (c2v > b2v || (c2v == b2v && c2i < b2i)) {
      b2v = c2v; b2i = c2i;
    }
  }
  if (lane == 0) {
    per[c * 2 + 0] = min(max(b1i, 4), 192);
    per[c * 2 + 1] = min(max(b2i, 4), 192);
  }
}

// ---------------- stage C: Mpinv via tridiagonal Thomas ----------------
__global__ __launch_bounds__(256) void build_mpinv_kernel(const int* __restrict__ per,
                                                          float* __restrict__ mp) {
  __shared__ int ii[384];
  __shared__ float ww[384];
  __shared__ float dd_[96], ee[96], cp[96], idt[96];
  __shared__ float ginv[96 * 97];
  __shared__ float outp[96 * 97];
  __shared__ int flag;
  int tid = threadIdx.x;
  int p = (blockIdx.x < 189) ? (4 + (int)blockIdx.x) : 384;
  if (tid == 0) flag = (p == 384) ? 1 : 0;
  __syncthreads();
  if (p != 384) {
    for (int i = tid; i < Cn * 2; i += 256)
      if (per[i] == p) flag = 1;
  }
  __syncthreads();
  if (!flag) return;

  int n = nanch(p);
  int m = (p >= n) ? n : p;
  float* dst = mp + mpoff(p);

  for (int j = tid; j < p; j += 256) {
    int i0, i1; float w;
    irow(j, p, n, i0, i1, w);
    ii[j] = i0; ww[j] = w;
  }
  for (int i = tid; i < m; i += 256) { dd_[i] = 0.f; ee[i] = 0.f; }
  __syncthreads();

  if (p >= n) {
    for (int j = tid; j < p; j += 256) {
      int i0 = ii[j]; float w = ww[j];
      int i1 = min(i0 + 1, n - 1);
      if (i1 == i0) {
        atomicAdd(&dd_[i0], 1.0f);
      } else {
        float a = 1.f - w, b = w;
        atomicAdd(&dd_[i0], a * a);
        atomicAdd(&dd_[i1], b * b);
        atomicAdd(&ee[i0], a * b);
      }
    }
  } else {
    for (int r = tid; r < p; r += 256) {
      int i0 = ii[r]; float w = ww[r];
      int i1 = min(i0 + 1, n - 1);
      float a, b; int c0 = i0, c1 = i1;
      if (i1 == i0) { a = 1.f; b = 0.f; c1 = -1; }
      else { a = 1.f - w; b = w; }
      dd_[r] = a * a + b * b;
      if (r < p - 1) {
        int j0 = ii[r + 1]; float w2 = ww[r + 1];
        int j1 = min(j0 + 1, n - 1);
        float a2, b2; int d0 = j0, d1 = j1;
        if (j1 == j0) { a2 = 1.f; b2 = 0.f; d1 = -2; }
        else { a2 = 1.f - w2; b2 = w2; }
        float s = 0.f;
        if (c0 == d0) s += a * a2;
        if (c0 == d1) s += a * b2;
        if (c1 == d0) s += b * a2;
        if (c1 == d1) s += b * b2;
        ee[r] = s;
      }
    }
  }
  __syncthreads();
  if (tid == 0) {
    float dt = dd_[0];
    idt[0] = 1.f / dt;
    for (int i = 1; i < m; ++i) {
      float c = ee[i - 1] * idt[i - 1];
      cp[i - 1] = c;
      dt = dd_[i] - ee[i - 1] * c;
      idt[i] = 1.f / dt;
    }
  }
  __syncthreads();
  if (tid < m) {
    int j = tid;
    float z = 1.f;
    ginv[j * 97 + j] = 1.f;
    for (int i = j + 1; i < m; ++i) {
      z = -cp[i - 1] * z;
      ginv[i * 97 + j] = z;
    }
    float xn = ginv[(m - 1) * 97 + j] * idt[m - 1];
    ginv[(m - 1) * 97 + j] = xn;
    for (int i = m - 2; i >= 0; --i) {
      float zi = (i >= j) ? ginv[i * 97 + j] : 0.f;
      xn = zi * idt[i] - cp[i] * xn;
      ginv[i * 97 + j] = xn;
    }
  }
  __syncthreads();
  if (p >= n) {
    for (int idx = tid; idx < p * n; idx += 256) {
      int t = idx / n, k = idx - t * n;
      int i0 = ii[t]; float w = ww[t];
      int i1 = min(i0 + 1, n - 1);
      dst[idx] = (1.f - w) * ginv[i0 * 97 + k] + w * ginv[i1 * 97 + k];
    }
  } else {
    for (int t = tid; t < p; t += 256) {
      for (int k = 0; k < n; ++k) outp[t * 97 + k] = 0.f;
      for (int j = 0; j < p; ++j) {
        float hv = ginv[t * 97 + j];
        int i0 = ii[j]; float w = ww[j];
        int i1 = min(i0 + 1, n - 1);
        outp[t * 97 + i0] += hv * (1.f - w);
        outp[t * 97 + i1] += hv * w;
      }
    }
    __syncthreads();
    for (int idx = tid; idx < p * n; idx += 256) {
      int t = idx / n, k = idx - t * n;
      dst[idx] = outp[t * 97 + k];
    }
  }
}

// ---------------- prep1: anchors^T + constsA merged ----------------
__device__ void at_body(int bid, const float* __restrict__ a12,
                        const float* __restrict__ a24, const float* __restrict__ a48,
                        const float* __restrict__ a96, float* __restrict__ at_tab,
                        float* tile) {
  int a = bid >> 3, d0 = (bid & 7) * 64;
  int n = (a == 0) ? 12 : (a == 1) ? 24 : (a == 2) ? 48 : 96;
  const float* src = (a == 0) ? a12 : (a == 1) ? a24 : (a == 2) ? a48 : a96;
  float* dst = at_tab + (long)apre(n) * 512;
  int tid = threadIdx.x;
  for (int i = tid; i < 64 * n; i += 256) {
    int dd = i / n, k = i - dd * n;
    tile[dd * 97 + k] = src[(long)(d0 + dd) * n + (long)k];
  }
  __syncthreads();
  for (int i = tid; i < n * 64; i += 256) {
    int k = i >> 6, dd = i & 63;
    dst[(long)k * 512 + d0 + dd] = tile[dd * 97 + k];
  }
  if (bid == 0) {
    for (int i = tid; i < 12 * 512; i += 256) at_tab[180L * 512 + i] = 0.f;
  }
}

__device__ void constsA_body(int bid, const float* __restrict__ i1w,
                             const float* __restrict__ i1b, const float* __restrict__ i2w,
                             const float* __restrict__ i2b, const float* __restrict__ sb,
                             float* __restrict__ cons, float* __restrict__ vbuf,
                             float* sv) {
  int s = bid / 96, r0 = (bid % 96) * 16;
  const float* inw = s ? i2w : i1w;
  const float* inb = s ? i2b : i1b;
  int tid = threadIdx.x;
  for (int i = tid; i < 512; i += 256) sv[i] = sb[i];
  __syncthreads();
  int lane = tid & 63, w = tid >> 6;
  for (int rr = 0; rr < 4; ++rr) {
    int r = r0 + w * 4 + rr;
    const float* row = inw + (long)r * 512;
    float part = 0.f;
    for (int kk = 0; kk < 8; ++kk) part += row[lane + 64 * kk] * sv[lane + 64 * kk];
    for (int off = 32; off > 0; off >>= 1) part += __shfl_down(part, off, 64);
    if (lane == 0) {
      float v = part + inb[r];
      if (r < 1024) cons[s * 1536 + r] = v;
      else vbuf[s * 512 + (r - 1024)] = v;
    }
  }
}

__global__ __launch_bounds__(256) void prep1(const float* __restrict__ a12,
                                             const float* __restrict__ a24,
                                             const float* __restrict__ a48,
                                             const float* __restrict__ a96,
                                             const float* __restrict__ i1w,
                                             const float* __restrict__ i1b,
                                             const float* __restrict__ i2w,
                                             const float* __restrict__ i2b,
                                             const float* __restrict__ sb,
                                             float* __restrict__ at_tab,
                                             float* __restrict__ cons,
                                             float* __restrict__ vbuf) {
  __shared__ float sm[64 * 97];
  int bid = blockIdx.x;
  if (bid < 32) at_body(bid, a12, a24, a48, a96, at_tab, sm);
  else constsA_body(bid - 32, i1w, i1b, i2w, i2b, sb, cons, vbuf, sm);
}

// ---------------- stage P2: WAfull = in_w @ A_cat ----------------
__global__ __launch_bounds__(256) void wa_gemm2(const float* __restrict__ iw0,
                                                const float* __restrict__ iw1,
                                                const float* __restrict__ atb,
                                                float* __restrict__ waf,
                                                float* __restrict__ qat,
                                                float* __restrict__ vat) {
  __shared__ float smem[2 * 32 * 68];
  float* As = smem;
  float* Ws = smem + 32 * 68;
  int bid = blockIdx.x;
  int s = bid / 72, r = bid % 72;
  int m0 = (r / 3) * 64, n0 = (r % 3) * 64;
  const float* A = s ? iw1 : iw0;
  float* wafs = waf + (long)s * 294912;
  int tid = threadIdx.x;
  int tm = tid & 15, tn = tid >> 4;
  float acc[4][4];
#pragma unroll
  for (int i = 0; i < 4; ++i)
#pragma unroll
    for (int j = 0; j < 4; ++j) acc[i][j] = 0.f;
  int row = tid >> 3, kc = (tid & 7) * 4;
  for (int k0 = 0; k0 < 512; k0 += 32) {
    float4 v = *(const float4*)&A[(long)(m0 + row) * 512 + k0 + kc];
    As[(kc + 0) * 68 + row] = v.x; As[(kc + 1) * 68 + row] = v.y;
    As[(kc + 2) * 68 + row] = v.z; As[(kc + 3) * 68 + row] = v.w;
    v = *(const float4*)&A[(long)(m0 + row + 32) * 512 + k0 + kc];
    As[(kc + 0) * 68 + row + 32] = v.x; As[(kc + 1) * 68 + row + 32] = v.y;
    As[(kc + 2) * 68 + row + 32] = v.z; As[(kc + 3) * 68 + row + 32] = v.w;
    v = *(const float4*)&atb[(long)(n0 + row) * 512 + k0 + kc];
    Ws[(kc + 0) * 68 + row] = v.x; Ws[(kc + 1) * 68 + row] = v.y;
    Ws[(kc + 2) * 68 + row] = v.z; Ws[(kc + 3) * 68 + row] = v.w;
    v = *(const float4*)&atb[(long)(n0 + row + 32) * 512 + k0 + kc];
    Ws[(kc + 0) * 68 + row + 32] = v.x; Ws[(kc + 1) * 68 + row + 32] = v.y;
    Ws[(kc + 2) * 68 + row + 32] = v.z; Ws[(kc + 3) * 68 + row + 32] = v.w;
    __syncthreads();
    for (int kk = 0; kk < 32; ++kk) {
      float4 a = *(const float4*)&As[kk * 68 + tm * 4];
      float4 w = *(const float4*)&Ws[kk * 68 + tn * 4];
      acc[0][0] += a.x * w.x; acc[0][1] += a.x * w.y; acc[0][2] += a.x * w.z; acc[0][3] += a.x * w.w;
      acc[1][0] += a.y * w.x; acc[1][1] += a.y * w.y; acc[1][2] += a.y * w.z; acc[1][3] += a.y * w.w;
      acc[2][0] += a.z * w.x; acc[2][1] += a.z * w.y; acc[2][2] += a.z * w.z; acc[2][3] += a.z * w.w;
      acc[3][0] += a.w * w.x; acc[3][1] += a.w * w.y; acc[3][2] += a.w * w.z; acc[3][3] += a.w * w.w;
    }
    __syncthreads();
  }
#pragma unroll
  for (int mi = 0; mi < 4; ++mi) {
    float4 o;
    o.x = acc[mi][0]; o.y = acc[mi][1]; o.z = acc[mi][2]; o.w = acc[mi][3];
    *(float4*)&wafs[(long)(m0 + tm * 4 + mi) * 192 + n0 + tn * 4] = o;
  }
  if (m0 < 512 || m0 >= 1024) {
    float* Ct = smem;
#pragma unroll
    for (int mi = 0; mi < 4; ++mi)
#pragma unroll
      for (int j = 0; j < 4; ++j)
        Ct[(tn * 4 + j) * 65 + tm * 4 + mi] = acc[mi][j];
    __syncthreads();
    float* dst = ((m0 < 512) ? qat : vat) + (long)s * 98304;
    int mr = m0 & 511;
    for (int i = tid; i < 64 * 64; i += 256) {
      int cc = i >> 6, rr = i & 63;
      dst[(long)(n0 + cc) * 512 + mr + rr] = Ct[cc * 65 + rr];
    }
  }
}

// ---------------- prep2 bodies ----------------
__device__ void constsB_body(int bid, const float* __restrict__ o1w,
                             const float* __restrict__ o1b, const float* __restrict__ o2w,
                             const float* __restrict__ o2b, const float* __restrict__ vbuf,
                             float* __restrict__ cons, float* vv) {
  int s = bid / 32, r0 = (bid % 32) * 16;
  const float* outw = s ? o2w : o1w;
  const float* outb = s ? o2b : o1b;
  int tid = threadIdx.x;
  for (int i = tid; i < 512; i += 256) vv[i] = vbuf[s * 512 + i];
  __syncthreads();
  int lane = tid & 63, w = tid >> 6;
  for (int rr = 0; rr < 4; ++rr) {
    int r = r0 + w * 4 + rr;
    const float* row = outw + (long)r * 512;
    float part = 0.f;
    for (int kk = 0; kk < 8; ++kk) part += row[lane + 64 * kk] * vv[lane + 64 * kk];
    for (int off = 32; off > 0; off >>= 1) part += __shfl_down(part, off, 64);
    if (lane == 0) cons[s * 1536 + 1024 + r] = part + outb[r];
  }
}

__device__ void mt_body(int bid, const float* __restrict__ qat,
                        const float* __restrict__ waf, float* __restrict__ mt,
                        float* As, float* Ws) {
  int s4h = bid / 9, t = bid % 9;
  int s = s4h >> 2, h = s4h & 3;
  int m0 = (t / 3) * 64, n0 = (t % 3) * 64;
  const float* A = qat + (long)s * 98304 + h * 128;
  const float* B = waf + (long)s * 294912 + 98304 + (long)(h * 128) * 192;
  float* C = mt + (long)s4h * 36864;
  int tid = threadIdx.x;
  int tm = tid & 15, tn = tid >> 4;
  float acc[4][4];
#pragma unroll
  for (int i = 0; i < 4; ++i)
#pragma unroll
    for (int j = 0; j < 4; ++j) acc[i][j] = 0.f;
  int row = tid >> 3, kc = (tid & 7) * 4;
  for (int k0 = 0; k0 < 128; k0 += 32) {
    float4 v = *(const float4*)&A[(long)(m0 + row) * 512 + k0 + kc];
    As[(kc + 0) * 68 + row] = v.x; As[(kc + 1) * 68 + row] = v.y;
    As[(kc + 2) * 68 + row] = v.z; As[(kc + 3) * 68 + row] = v.w;
    v = *(const float4*)&A[(long)(m0 + row + 32) * 512 + k0 + kc];
    As[(kc + 0) * 68 + row + 32] = v.x; As[(kc + 1) * 68 + row + 32] = v.y;
    As[(kc + 2) * 68 + row + 32] = v.z; As[(kc + 3) * 68 + row + 32] = v.w;
    for (int l = tid; l < 512; l += 256) {
      int i = l >> 4, kq = (l & 15) * 4;
      float4 b = *(const float4*)&B[(long)(k0 + i) * 192 + n0 + kq];
      Ws[i * 68 + kq + 0] = b.x; Ws[i * 68 + kq + 1] = b.y;
      Ws[i * 68 + kq + 2] = b.z; Ws[i * 68 + kq + 3] = b.w;
    }
    __syncthreads();
    for (int kk = 0; kk < 32; ++kk) {
      float4 a = *(const float4*)&As[kk * 68 + tm * 4];
      float4 w = *(const float4*)&Ws[kk * 68 + tn * 4];
      acc[0][0] += a.x * w.x; acc[0][1] += a.x * w.y; acc[0][2] += a.x * w.z; acc[0][3] += a.x * w.w;
      acc[1][0] += a.y * w.x; acc[1][1] += a.y * w.y; acc[1][2] += a.y * w.z; acc[1][3] += a.y * w.w;
      acc[2][0] += a.z * w.x; acc[2][1] += a.z * w.y; acc[2][2] += a.z * w.z; acc[2][3] += a.z * w.w;
      acc[3][0] += a.w * w.x; acc[3][1] += a.w * w.y; acc[3][2] += a.w * w.z; acc[3][3] += a.w * w.w;
    }
    __syncthreads();
  }
#pragma unroll
  for (int mi = 0; mi < 4; ++mi) {
    float4 o;
    o.x = acc[mi][0]; o.y = acc[mi][1]; o.z = acc[mi][2]; o.w = acc[mi][3];
    *(float4*)&C[(long)(m0 + tm * 4 + mi) * 192 + n0 + tn * 4] = o;
  }
}

__device__ void sc_body(int bid, const float* __restrict__ qat,
                        const float* __restrict__ waf, const float* __restrict__ cons,
                        float* __restrict__ def, float* qcl, float* kbl) {
  int s = bid >> 2, h = bid & 3;
  int tid = threadIdx.x;
  const float* qc = cons + s * 1536;
  const float* kb = qc + 512;
  if (tid < 128) {
    qcl[tid] = qc[h * 128 + tid];
    kbl[tid] = kb[h * 128 + tid];
  }
  __syncthreads();
  const float* katb = waf + (long)s * 294912 + 98304;
  const float* qats = qat + (long)s * 98304;
  float* dtab = def + (long)(s * 4 + h) * 192;
  float* etab = def + 1536 + (long)(s * 4 + h) * 192;
  float* ftab = def + 3072 + (s * 4 + h);
  if (tid < 192) {
    float acc = 0.f;
    for (int i = 0; i < 128; ++i) acc += katb[(long)(h * 128 + i) * 192 + tid] * qcl[i];
    dtab[tid] = acc;
    float acc2 = 0.f;
    const float* qr = qats + (long)tid * 512 + h * 128;
    for (int i = 0; i < 128; ++i) acc2 += qr[i] * kbl[i];
    etab[tid] = acc2;
  }
  if (tid < 64) {
    float acc = 0.f;
    for (int i = tid; i < 128; i += 64) acc += qcl[i] * kbl[i];
    for (int off = 32; off > 0; off >>= 1) acc += __shfl_down(acc, off, 64);
    if (tid == 0) *ftab = acc;
  }
}

__device__ void ova_body(int bid, const float* __restrict__ ow0,
                         const float* __restrict__ ow1, const float* __restrict__ vat,
                         float* __restrict__ ovt, float* As, float* Ws) {
  int s = bid / 96, r = bid % 96;
  int h = r / 24, r2 = r % 24;
  int m0 = (r2 / 8) * 64, n0 = (r2 % 8) * 64;
  const float* A = vat + (long)s * 98304 + h * 128;
  const float* W = (s ? ow1 : ow0) + h * 128;
  float* C = ovt + ((long)(s * 4 + h) * 192) * 512;
  int tid = threadIdx.x;
  int tm = tid & 15, tn = tid >> 4;
  float acc[4][4];
#pragma unroll
  for (int i = 0; i < 4; ++i)
#pragma unroll
    for (int j = 0; j < 4; ++j) acc[i][j] = 0.f;
  int row = tid >> 3, kc = (tid & 7) * 4;
  for (int k0 = 0; k0 < 128; k0 += 32) {
    float4 v = *(const float4*)&A[(long)(m0 + row) * 512 + k0 + kc];
    As[(kc + 0) * 68 + row] = v.x; As[(kc + 1) * 68 + row] = v.y;
    As[(kc + 2) * 68 + row] = v.z; As[(kc + 3) * 68 + row] = v.w;
    v = *(const float4*)&A[(long)(m0 + row + 32) * 512 + k0 + kc];
    As[(kc + 0) * 68 + row + 32] = v.x; As[(kc + 1) * 68 + row + 32] = v.y;
    As[(kc + 2) * 68 + row + 32] = v.z; As[(kc + 3) * 68 + row + 32] = v.w;
    v = *(const float4*)&W[(long)(n0 + row) * 512 + k0 + kc];
    Ws[(kc + 0) * 68 + row] = v.x; Ws[(kc + 1) * 68 + row] = v.y;
    Ws[(kc + 2) * 68 + row] = v.z; Ws[(kc + 3) * 68 + row] = v.w;
    v = *(const float4*)&W[(long)(n0 + row + 32) * 512 + k0 + kc];
    Ws[(kc + 0) * 68 + row + 32] = v.x; Ws[(kc + 1) * 68 + row + 32] = v.y;
    Ws[(kc + 2) * 68 + row + 32] = v.z; Ws[(kc + 3) * 68 + row + 32] = v.w;
    __syncthreads();
    for (int kk = 0; kk < 32; ++kk) {
      float4 a = *(const float4*)&As[kk * 68 + tm * 4];
      float4 w = *(const float4*)&Ws[kk * 68 + tn * 4];
      acc[0][0] += a.x * w.x; acc[0][1] += a.x * w.y; acc[0][2] += a.x * w.z; acc[0][3] += a.x * w.w;
      acc[1][0] += a.y * w.x; acc[1][1] += a.y * w.y; acc[1][2] += a.y * w.z; acc[1][3] += a.y * w.w;
      acc[2][0] += a.z * w.x; acc[2][1] += a.z * w.y; acc[2][2] += a.z * w.z; acc[2][3] += a.z * w.w;
      acc[3][0] += a.w * w.x; acc[3][1] += a.w * w.y; acc[3][2] += a.w * w.z; acc[3][3] += a.w * w.w;
    }
    __syncthreads();
  }
#pragma unroll
  for (int mi = 0; mi < 4; ++mi) {
    float4 o;
    o.x = acc[mi][0]; o.y = acc[mi][1]; o.z = acc[mi][2]; o.w = acc[mi][3];
    *(float4*)&C[(long)(m0 + tm * 4 + mi) * 512 + n0 + tn * 4] = o;
  }
}

__global__ __launch_bounds__(256) void prep2(const float* __restrict__ o1w,
                                             const float* __restrict__ o1b,
                                             const float* __restrict__ o2w,
                                             const float* __restrict__ o2b,
                                             const float* __restrict__ vbuf,
                                             float* __restrict__ cons,
                                             const float* __restrict__ qat,
                                             const float* __restrict__ waf,
                                             float* __restrict__ mtab,
                                             float* __restrict__ def,
                                             const float* __restrict__ vat,
                                             float* __restrict__ ovt) {
  __shared__ float sm[2 * 32 * 68];
  int bid = blockIdx.x;
  if (bid < 64) constsB_body(bid, o1w, o1b, o2w, o2b, vbuf, cons, sm);
  else if (bid < 136) mt_body(bid - 64, qat, waf, mtab, sm, sm + 32 * 68);
  else if (bid < 144) sc_body(bid - 136, qat, waf, cons, def, sm, sm + 128);
  else ova_body(bid - 144, o1w, o2w, vat, ovt, sm, sm + 32 * 68);
}

// ---------------- stage B1: attn_a — Z, scores, softmax, zh -> zcat ----------------
__global__ __launch_bounds__(256) void attn_a(
    const float* __restrict__ xT, const int* __restrict__ per,
    const float* __restrict__ mp, const float* __restrict__ mt,
    const float* __restrict__ def, float* __restrict__ zc) {
  __shared__ float xb[8 * 384];
  __shared__ float Z[8 * 1248];
  __shared__ float zl[8 * 96];
  __shared__ float arb[8 * 384];
  __shared__ float qkc[32];
  float* scp = xb;

  int tid = threadIdx.x;
  int bid = blockIdx.x;
  int slot = bid & 1;
  int c = (bid >> 1) & 127;
  int b0 = (bid >> 8) * 8;
  int p = per[c * 2 + slot];
  int n = nanch(p);
  int np = Tn / p;
  int n1 = n + 1;
  float s = sqrtf((float)p / (float)n);
  float s2 = s * s;
  const float rscale = 0.08838834764831845f;
  int pre = apre(n);
  const float* mpp = mp + mpoff(p);
  const float* dt = def + (long)(slot * 4) * 192;
  const float* et = def + 1536 + (long)(slot * 4) * 192;
  const float* ft = def + 3072 + slot * 4;
  const float* mtb = mt + (long)(slot * 4) * 36864;

  for (int g = 0; g < 8; ++g)
    for (int t = tid; t < Tn; t += 256)
      xb[g * 384 + t] = xT[((long)c * Bn + b0 + g) * Tn + t];
  __syncthreads();

  // Ph1: Z = patches @ Mpinv; thread = (j, 16-k chunk, g-pair)
  // Mpinv row loads are j-independent -> wave-broadcast / L1-resident.
  {
    int nkc = (n + 15) >> 4;
    int items = np * nkc * 4;
    for (int idx = tid; idx < items; idx += 256) {
      int gg = idx & 3;
      int t4 = idx >> 2;
      int j = t4 / nkc, kc_ = t4 - j * nkc;
      int k0 = kc_ * 16;
      int jb = j * p;
      const float* xr0 = xb + (gg * 2) * 384 + jb;
      const float* xr1 = xr0 + 384;
      const float* mrow = mpp + k0;
      float a0[16], a1[16];
#pragma unroll
      for (int e = 0; e < 16; ++e) { a0[e] = 0.f; a1[e] = 0.f; }
      for (int t = 0; t < p; ++t) {
        float x0 = xr0[t], x1 = xr1[t];
        const float* mr = mrow + (long)t * n;
        float4 m0 = *(const float4*)&mr[0];
        float4 m1 = *(const float4*)&mr[4];
        float4 m2 = *(const float4*)&mr[8];
        float4 m3 = *(const float4*)&mr[12];
        a0[0] += m0.x * x0;  a0[1] += m0.y * x0;  a0[2] += m0.z * x0;  a0[3] += m0.w * x0;
        a0[4] += m1.x * x0;  a0[5] += m1.y * x0;  a0[6] += m1.z * x0;  a0[7] += m1.w * x0;
        a0[8] += m2.x * x0;  a0[9] += m2.y * x0;  a0[10] += m2.z * x0; a0[11] += m2.w * x0;
        a0[12] += m3.x * x0; a0[13] += m3.y * x0; a0[14] += m3.z * x0; a0[15] += m3.w * x0;
        a1[0] += m0.x * x1;  a1[1] += m0.y * x1;  a1[2] += m0.z * x1;  a1[3] += m0.w * x1;
        a1[4] += m1.x * x1;  a1[5] += m1.y * x1;  a1[6] += m1.z * x1;  a1[7] += m1.w * x1;
        a1[8] += m2.x * x1;  a1[9] += m2.y * x1;  a1[10] += m2.z * x1; a1[11] += m2.w * x1;
        a1[12] += m3.x * x1; a1[13] += m3.y * x1; a1[14] += m3.z * x1; a1[15] += m3.w * x1;
      }
      int kcnt = min(16, n - k0);
      float* z0 = Z + (gg * 2) * 1248 + j * n1 + k0;
      float* z1 = z0 + 1248;
      for (int e = 0; e < kcnt; ++e) { z0[e] = a0[e]; z1[e] = a1[e]; }
    }
  }
  __syncthreads();

  for (int idx = tid; idx < 8 * n; idx += 256) {
    int g = idx / n, k = idx - g * n;
    zl[g * 96 + k] = Z[g * 1248 + (np - 1) * n1 + k];
  }
  __syncthreads();

  {
    int pair = tid >> 3, l = tid & 7;
    int g = pair >> 2, h = pair & 3;
    const float* eh = et + h * 192 + pre;
    float acc = 0.f;
    for (int j = l; j < n; j += 8) acc += eh[j] * zl[g * 96 + j];
    for (int off = 4; off > 0; off >>= 1) acc += __shfl_down(acc, off, 8);
    if (l == 0) qkc[g * 4 + h] = s * acc + ft[h];
  }
  {
    int tot = 4 * n;
    for (int idx = tid; idx < tot; idx += 256) {
      int h = idx / n, k = idx - h * n;
      const float* mtc = mtb + (long)h * 36864 + (long)pre * 192 + pre + k;
      float a[8];
#pragma unroll
      for (int g = 0; g < 8; ++g) a[g] = 0.f;
      for (int j0 = 0; j0 < n; j0 += 4) {
        float4 zb[8];
#pragma unroll
        for (int g = 0; g < 8; ++g) zb[g] = *(const float4*)&zl[g * 96 + j0];
#pragma unroll
        for (int c4 = 0; c4 < 4; ++c4) {
          float mv = mtc[(long)(j0 + c4) * 192];
#pragma unroll
          for (int g = 0; g < 8; ++g) {
            float zv = (c4 == 0) ? zb[g].x : (c4 == 1) ? zb[g].y : (c4 == 2) ? zb[g].z : zb[g].w;
            a[g] += mv * zv;
          }
        }
      }
      float dv = dt[h * 192 + pre + k];
#pragma unroll
      for (int g = 0; g < 8; ++g) arb[g * 384 + h * 96 + k] = s2 * a[g] + s * dv;
    }
  }
  __syncthreads();

  // scores
  {
    int fnp = 4 * np;
    int tot = 8 * fnp;
    for (int idx = tid; idx < tot; idx += 256) {
      int g = idx / fnp;
      int r = idx - g * fnp;
      int h = r / np, j = r - h * np;
      const float* ap = arb + g * 384 + h * 96;
      const float* zp = Z + g * 1248 + j * n1;
      float acc = 0.f;
      for (int k = 0; k < n; ++k) acc += ap[k] * zp[k];
      scp[g * 384 + h * np + j] = (acc + qkc[g * 4 + h]) * rscale;
    }
  }
  __syncthreads();

  // softmax
  {
    int pair = tid >> 3, l = tid & 7;
    int g = pair >> 2, h = pair & 3;
    float* sp = scp + g * 384 + h * np;
    float m = -1e30f;
    for (int j = l; j < np; j += 8) m = fmaxf(m, sp[j]);
    for (int off = 4; off > 0; off >>= 1) m = fmaxf(m, __shfl_xor(m, off, 8));
    float lsum = 0.f;
    for (int j = l; j < np; j += 8) { float e = expf(sp[j] - m); sp[j] = e; lsum += e; }
    for (int off = 4; off > 0; off >>= 1) lsum += __shfl_xor(lsum, off, 8);
    float il = 1.f / lsum;
    for (int j = l; j < np; j += 8) sp[j] *= il;
  }
  __syncthreads();

  // zh
  {
    int fn = 4 * n;
    int tot = 8 * fn;
    for (int idx = tid; idx < tot; idx += 256) {
      int g = idx / fn;
      int r = idx - g * fn;
      int h = r / n, k = r - h * n;
      const float* sp = scp + g * 384 + h * np;
      const float* zp = Z + g * 1248 + k;
      float acc = 0.f;
      for (int j = 0; j < np; ++j) acc += sp[j] * zp[j * n1];
      arb[g * 384 + h * 96 + k] = acc;
    }
  }
  __syncthreads();

  // write zcat (s-scaled)
  {
    long rowb = ((long)slot * 128 + c) * 16 + b0;
    int fn5 = 5 * n;
    int tot = 8 * fn5;
    for (int idx = tid; idx < tot; idx += 256) {
      int g = idx / fn5, r = idx - g * fn5;
      int seg = r / n, k = r - seg * n;
      float v = (seg == 0) ? zl[g * 96 + k] : arb[g * 384 + (seg - 1) * 96 + k];
      zc[(rowb + g) * 480 + seg * 96 + k] = s * v;
    }
  }
}

// ---------------- stage B2: attn_y ----------------
__global__ __launch_bounds__(256) void attn_y(
    const int* __restrict__ per, const float* __restrict__ zc,
    const float* __restrict__ at_tab, const float* __restrict__ ovt,
    const float* __restrict__ cons, const float* __restrict__ sb,
    const float* __restrict__ l1g, const float* __restrict__ l1b,
    const float* __restrict__ l2g, const float* __restrict__ l2b,
    float* __restrict__ comb) {
  __shared__ float zbuf[16 * 480];
  __shared__ float red[128];
  __shared__ float stats[32];
  int tid = threadIdx.x;
  int bid = blockIdx.x;
  int slot = bid & 1, c = bid >> 1;
  int p = per[c * 2 + slot];
  int n = nanch(p);
  int pre = apre(n);
  const float* atb = at_tab + (long)pre * 512;
  const float* oc = cons + slot * 1536 + 1024;
  const float* lng = slot ? l2g : l1g;
  const float* lnb = slot ? l2b : l1b;
  long rowb = ((long)slot * 128 + c) * 16;
  int fn5 = 5 * n;
  for (int idx = tid; idx < 16 * fn5; idx += 256) {
    int g = idx / fn5, r = idx - g * fn5;
    int seg = r / n, k = r - seg * n;
    zbuf[g * 480 + seg * 96 + k] = zc[(rowb + g) * 480 + seg * 96 + k];
  }
  __syncthreads();
  int d0 = 2 * tid;
  float acc0[16], acc1[16];
#pragma unroll
  for (int r = 0; r < 16; ++r) { acc0[r] = 0.f; acc1[r] = 0.f; }
  for (int seg = 0; seg < 5; ++seg) {
    const float* wt = (seg == 0) ? atb
                                 : (ovt + ((long)(slot * 4 + seg - 1) * 192 + pre) * 512);
    int zoff = seg * 96;
    for (int k0 = 0; k0 < n; k0 += 4) {
      float4 zv[16];
#pragma unroll
      for (int r = 0; r < 16; ++r) zv[r] = *(const float4*)&zbuf[r * 480 + zoff + k0];
#pragma unroll
      for (int c4 = 0; c4 < 4; ++c4) {
        float2 w = *(const float2*)&wt[(long)(k0 + c4) * 512 + d0];
#pragma unroll
        for (int r = 0; r < 16; ++r) {
          float z = (c4 == 0) ? zv[r].x : (c4 == 1) ? zv[r].y : (c4 == 2) ? zv[r].z : zv[r].w;
          acc0[r] += w.x * z;
          acc1[r] += w.y * z;
        }
      }
    }
  }
  float2 sbv = *(const float2*)&sb[d0];
  float2 ocv = *(const float2*)&oc[d0];
  float s0 = sbv.x + ocv.x, s1 = sbv.y + ocv.y;
#pragma unroll
  for (int r = 0; r < 16; ++r) { acc0[r] += s0; acc1[r] += s1; }
  float ps[32];
#pragma unroll
  for (int r = 0; r < 16; ++r) {
    ps[2 * r] = acc0[r] + acc1[r];
    ps[2 * r + 1] = acc0[r] * acc0[r] + acc1[r] * acc1[r];
  }
  int w = tid >> 6, lane = tid & 63;
  for (int off = 32; off > 0; off >>= 1) {
#pragma unroll
    for (int i = 0; i < 32; ++i) ps[i] += __shfl_down(ps[i], off, 64);
  }
  if (lane == 0) {
#pragma unroll
    for (int i = 0; i < 32; ++i) red[w * 32 + i] = ps[i];
  }
  __syncthreads();
  if (tid < 16) {
    int r = tid;
    float ssum = red[2 * r] + red[32 + 2 * r] + red[64 + 2 * r] + red[96 + 2 * r];
    float qsum = red[2 * r + 1] + red[32 + 2 * r + 1] + red[64 + 2 * r + 1] + red[96 + 2 * r + 1];
    float mu = ssum / 512.f;
    float var = qsum / 512.f - mu * mu;
    stats[2 * r] = mu;
    stats[2 * r + 1] = rsqrtf(var + 1e-5f);
  }
  __syncthreads();
  float2 gv = *(const float2*)&lng[d0];
  float2 bv = *(const float2*)&lnb[d0];
#pragma unroll
  for (int r = 0; r < 16; ++r) {
    float mu = stats[2 * r], rstd = stats[2 * r + 1];
    long base = ((long)r * Cn + c) * 1536 + slot * 512;
    float2 o;
    o.x = (acc0[r] - mu) * rstd * gv.x + bv.x;
    o.y = (acc1[r] - mu) * rstd * gv.y + bv.y;
    *(float2*)&comb[base + d0] = o;
  }
}

// ---------------- stage D: trend ----------------
__global__ __launch_bounds__(256) void trend_kernel(const float* __restrict__ xT,
                                                    const float* __restrict__ mp384,
                                                    const float* __restrict__ at96,
                                                    const float* __restrict__ sb,
                                                    float* __restrict__ comb) {
  __shared__ float xb[Bn * Tn];
  __shared__ float Ztr[Bn * 97];
  int c = blockIdx.x, tid = threadIdx.x;
  for (int i = tid; i < Bn * Tn; i += 256) xb[i] = xT[(long)c * Bn * Tn + i];
  __syncthreads();
  for (int idx = tid; idx < 4 * 96; idx += 256) {
    int bq = idx / 96, k = idx - bq * 96;
    const float* x0 = xb + (bq * 4 + 0) * Tn;
    const float* x1 = xb + (bq * 4 + 1) * Tn;
    const float* x2 = xb + (bq * 4 + 2) * Tn;
    const float* x3 = xb + (bq * 4 + 3) * Tn;
    const float* mk = mp384 + k;
    float a0 = 0.f, a1 = 0.f, a2 = 0.f, a3 = 0.f;
    for (int t = 0; t < Tn; ++t) {
      float m = mk[(long)t * 96];
      a0 += m * x0[t]; a1 += m * x1[t]; a2 += m * x2[t]; a3 += m * x3[t];
    }
    Ztr[(bq * 4 + 0) * 97 + k] = a0;
    Ztr[(bq * 4 + 1) * 97 + k] = a1;
    Ztr[(bq * 4 + 2) * 97 + k] = a2;
    Ztr[(bq * 4 + 3) * 97 + k] = a3;
  }
  __syncthreads();
  float acc0[Bn], acc1[Bn];
#pragma unroll
  for (int b = 0; b < Bn; ++b) { acc0[b] = 0.f; acc1[b] = 0.f; }
  for (int k = 0; k < 96; ++k) {
    float w0 = at96[(long)k * 512 + tid];
    float w1 = at96[(long)k * 512 + 256 + tid];
#pragma unroll
    for (int b = 0; b < Bn; ++b) {
      float z = Ztr[b * 97 + k];
      acc0[b] += w0 * z;
      acc1[b] += w1 * z;
    }
  }
  float s0 = sb[tid], s1 = sb[256 + tid];
#pragma unroll
  for (int b = 0; b < Bn; ++b) {
    long base = ((long)b * Cn + c) * 1536 + 1024;
    comb[base + tid] = 2.f * acc0[b] + s0;
    comb[base + 256 + tid] = 2.f * acc1[b] + s1;
  }
}

// ---------------- stage E1: fusion GEMM-1, split-K halves, double-buffered LDS ----------------
__global__ __launch_bounds__(256) void gemm1_part(const float* __restrict__ A,
                                                  const float* __restrict__ W,
                                                  float* __restrict__ C0,
                                                  float* __restrict__ C1) {
  __shared__ float As[2][32 * 68];
  __shared__ float Ws[2][32 * 68];
  int bid = blockIdx.x;
  int kh = bid >> 8;
  int r = bid & 255;
  int m0 = (r >> 3) * 64, n0 = (r & 7) * 64;
  float* C = kh ? C1 : C0;
  const float* Ab = A + kh * 768;
  const float* Wb = W + kh * 768;
  int tid = threadIdx.x;
  int tm = tid & 15, tn = tid >> 4;
  int row = tid >> 3, kc = (tid & 7) * 4;
  float acc[4][4];
#pragma unroll
  for (int i = 0; i < 4; ++i)
#pragma unroll
    for (int j = 0; j < 4; ++j) acc[i][j] = 0.f;
  float4 ra0, ra1, rw0, rw1;
  auto ld = [&](int k0) {
    ra0 = *(const float4*)&Ab[(long)(m0 + row) * 1536 + k0 + kc];
    ra1 = *(const float4*)&Ab[(long)(m0 + row + 32) * 1536 + k0 + kc];
    rw0 = *(const float4*)&Wb[(long)(n0 + row) * 1536 + k0 + kc];
    rw1 = *(const float4*)&Wb[(long)(n0 + row + 32) * 1536 + k0 + kc];
  };
  auto st = [&](int b) {
    float* as = As[b]; float* ws = Ws[b];
    as[(kc + 0) * 68 + row] = ra0.x; as[(kc + 1) * 68 + row] = ra0.y;
    as[(kc + 2) * 68 + row] = ra0.z; as[(kc + 3) * 68 + row] = ra0.w;
    as[(kc + 0) * 68 + row + 32] = ra1.x; as[(kc + 1) * 68 + row + 32] = ra1.y;
    as[(kc + 2) * 68 + row + 32] = ra1.z; as[(kc + 3) * 68 + row + 32] = ra1.w;
    ws[(kc + 0) * 68 + row] = rw0.x; ws[(kc + 1) * 68 + row] = rw0.y;
    ws[(kc + 2) * 68 + row] = rw0.z; ws[(kc + 3) * 68 + row] = rw0.w;
    ws[(kc + 0) * 68 + row + 32] = rw1.x; ws[(kc + 1) * 68 + row + 32] = rw1.y;
    ws[(kc + 2) * 68 + row + 32] = rw1.z; ws[(kc + 3) * 68 + row + 32] = rw1.w;
  };
  ld(0); st(0); __syncthreads();
  ld(32);
  for (int ch = 0; ch < 24; ++ch) {
    int cur = ch & 1;
    const float* as = As[cur];
    const float* ws = Ws[cur];
    for (int kk = 0; kk < 32; ++kk) {
      float4 a = *(const float4*)&as[kk * 68 + tm * 4];
      float4 w = *(const float4*)&ws[kk * 68 + tn * 4];
      acc[0][0] += a.x * w.x; acc[0][1] += a.x * w.y; acc[0][2] += a.x * w.z; acc[0][3] += a.x * w.w;
      acc[1][0] += a.y * w.x; acc[1][1] += a.y * w.y; acc[1][2] += a.y * w.z; acc[1][3] += a.y * w.w;
      acc[2][0] += a.z * w.x; acc[2][1] += a.z * w.y; acc[2][2] += a.z * w.z; acc[2][3] += a.z * w.w;
      acc[3][0] += a.w * w.x; acc[3][1] += a.w * w.y; acc[3][2] += a.w * w.z; acc[3][3] += a.w * w.w;
    }
    __syncthreads();
    if (ch + 1 < 24) {
      st(cur ^ 1);
      if (ch + 2 < 24) ld((ch + 2) * 32);
      __syncthreads();
    }
  }
#pragma unroll
  for (int mi = 0; mi < 4; ++mi) {
    float4 o;
    o.x = acc[mi][0]; o.y = acc[mi][1]; o.z = acc[mi][2]; o.w = acc[mi][3];
    *(float4*)&C[(long)(m0 + tm * 4 + mi) * 512 + n0 + tn * 4] = o;
  }
}

// ---------------- stage E2: GEMM-2, A = gelu(H0+H1+fb1) fused in staging ----------------
__global__ __launch_bounds__(256) void gemm2_fused(const float* __restrict__ H0,
                                                   const float* __restrict__ H1,
                                                   const float* __restrict__ fb1,
                                                   const float* __restrict__ W,
                                                   const float* __restrict__ fb2,
                                                   float* __restrict__ C) {
  __shared__ float As[32 * 68];
  __shared__ float Ws[32 * 68];
  int m0 = (blockIdx.x >> 3) * 64, n0 = (blockIdx.x & 7) * 64;
  int tid = threadIdx.x;
  int tm = tid & 15, tn = tid >> 4;
  float acc[4][4];
#pragma unroll
  for (int i = 0; i < 4; ++i)
#pragma unroll
    for (int j = 0; j < 4; ++j) acc[i][j] = 0.f;
  int row = tid >> 3, kc = (tid & 7) * 4;
  for (int k0 = 0; k0 < 512; k0 += 32) {
    float4 bs = *(const float4*)&fb1[k0 + kc];
    float4 h0 = *(const float4*)&H0[(long)(m0 + row) * 512 + k0 + kc];
    float4 h1 = *(const float4*)&H1[(long)(m0 + row) * 512 + k0 + kc];
    float4 v;
    v.x = h0.x + h1.x + bs.x; v.y = h0.y + h1.y + bs.y;
    v.z = h0.z + h1.z + bs.z; v.w = h0.w + h1.w + bs.w;
    v.x = 0.5f * v.x * (1.f + erff(v.x * 0.7071067811865475f));
    v.y = 0.5f * v.y * (1.f + erff(v.y * 0.7071067811865475f));
    v.z = 0.5f * v.z * (1.f + erff(v.z * 0.7071067811865475f));
    v.w = 0.5f * v.w * (1.f + erff(v.w * 0.7071067811865475f));
    As[(kc + 0) * 68 + row] = v.x; As[(kc + 1) * 68 + row] = v.y;
    As[(kc + 2) * 68 + row] = v.z; As[(kc + 3) * 68 + row] = v.w;
    h0 = *(const float4*)&H0[(long)(m0 + row + 32) * 512 + k0 + kc];
    h1 = *(const float4*)&H1[(long)(m0 + row + 32) * 512 + k0 + kc];
    v.x = h0.x + h1.x + bs.x; v.y = h0.y + h1.y + bs.y;
    v.z = h0.z + h1.z + bs.z; v.w = h0.w + h1.w + bs.w;
    v.x = 0.5f * v.x * (1.f + erff(v.x * 0.7071067811865475f));
    v.y = 0.5f * v.y * (1.f + erff(v.y * 0.7071067811865475f));
    v.z = 0.5f * v.z * (1.f + erff(v.z * 0.7071067811865475f));
    v.w = 0.5f * v.w * (1.f + erff(v.w * 0.7071067811865475f));
    As[(kc + 0) * 68 + row + 32] = v.x; As[(kc + 1) * 68 + row + 32] = v.y;
    As[(kc + 2) * 68 + row + 32] = v.z; As[(kc + 3) * 68 + row + 32] = v.w;
    float4 wv = *(const float4*)&W[(long)(n0 + row) * 512 + k0 + kc];
    Ws[(kc + 0) * 68 + row] = wv.x; Ws[(kc + 1) * 68 + row] = wv.y;
    Ws[(kc + 2) * 68 + row] = wv.z; Ws[(kc + 3) * 68 + row] = wv.w;
    wv = *(const float4*)&W[(long)(n0 + row + 32) * 512 + k0 + kc];
    Ws[(kc + 0) * 68 + row + 32] = wv.x; Ws[(kc + 1) * 68 + row + 32] = wv.y;
    Ws[(kc + 2) * 68 + row + 32] = wv.z; Ws[(kc + 3) * 68 + row + 32] = wv.w;
    __syncthreads();
    for (int kk = 0; kk < 32; ++kk) {
      float4 a = *(const float4*)&As[kk * 68 + tm * 4];
      float4 w = *(const float4*)&Ws[kk * 68 + tn * 4];
      acc[0][0] += a.x * w.x; acc[0][1] += a.x * w.y; acc[0][2] += a.x * w.z; acc[0][3] += a.x * w.w;
      acc[1][0] += a.y * w.x; acc[1][1] += a.y * w.y; acc[1][2] += a.y * w.z; acc[1][3] += a.y * w.w;
      acc[2][0] += a.z * w.x; acc[2][1] += a.z * w.y; acc[2][2] += a.z * w.z; acc[2][3] += a.z * w.w;
      acc[3][0] += a.w * w.x; acc[3][1] += a.w * w.y; acc[3][2] += a.w * w.z; acc[3][3] += a.w * w.w;
    }
    __syncthreads();
  }
  float b0v = fb2[n0 + tn * 4 + 0], b1v = fb2[n0 + tn * 4 + 1];
  float b2v = fb2[n0 + tn * 4 + 2], b3v = fb2[n0 + tn * 4 + 3];
#pragma unroll
  for (int mi = 0; mi < 4; ++mi) {
    float4 o;
    o.x = acc[mi][0] + b0v; o.y = acc[mi][1] + b1v;
    o.z = acc[mi][2] + b2v; o.w = acc[mi][3] + b3v;
    *(float4*)&C[(long)(m0 + tm * 4 + mi) * 512 + n0 + tn * 4] = o;
  }
}

extern "C" void kernel_launch(void* const* d_in, const int* in_sizes, int n_in,
                              void* d_out, int out_size, void* d_ws, size_t ws_size,
                              hipStream_t stream) {
  const float* x    = (const float*)d_in[0];
  const float* a12  = (const float*)d_in[1];
  const float* a24  = (const float*)d_in[2];
  const float* a48  = (const float*)d_in[3];
  const float* a96  = (const float*)d_in[4];
  const float* sb   = (const float*)d_in[5];
  const float* g1iw = (const float*)d_in[6];
  const float* g1ib = (const float*)d_in[7];
  const float* g1ow = (const float*)d_in[8];
  const float* g1ob = (const float*)d_in[9];
  const float* g1lg = (const float*)d_in[10];
  const float* g1lb = (const float*)d_in[11];
  const float* g2iw = (const float*)d_in[12];
  const float* g2ib = (const float*)d_in[13];
  const float* g2ow = (const float*)d_in[14];
  const float* g2ob = (const float*)d_in[15];
  const float* g2lg = (const float*)d_in[16];
  const float* g2lb = (const float*)d_in[17];
  const float* fw1  = (const float*)d_in[18];
  const float* fb1  = (const float*)d_in[19];
  const float* fw2  = (const float*)d_in[20];
  const float* fb2  = (const float*)d_in[21];

  if (ws_size < (size_t)WS_FLOATS * sizeof(float)) return;

  float* ws   = (float*)d_ws;
  float* xT   = ws + OFF_XT;
  float* avg  = ws + OFF_AVG;
  int*   per  = (int*)(ws + OFF_PER);
  float* mp   = ws + OFF_MP;
  float* atb  = ws + OFF_AT;
  float* waf  = ws + OFF_WAF;
  float* qat  = ws + OFF_QAT;
  float* vat  = ws + OFF_VAT;
  float* ovt  = ws + OFF_OVT;
  float* cons = ws + OFF_CON;
  float* vbuf = ws + OFF_VB;
  float* mtab = ws + OFF_MT;
  float* def  = ws + OFF_DEF;
  float* zc   = ws + OFF_ZC;
  float* comb = ws + OFF_COMB;
  float* hbuf = ws + OFF_H;
  float* hbu2 = ws + OFF_H2;
  float* out  = (float*)d_out;

  transpose_kernel<<<192, 256, 0, stream>>>(x, xT);
  acf_kernel<<<Cn * 6, 256, 0, stream>>>(xT, avg);
  periods_kernel<<<32, 256, 0, stream>>>(avg, per);
  build_mpinv_kernel<<<190, 256, 0, stream>>>(per, mp);
  prep1<<<224, 256, 0, stream>>>(a12, a24, a48, a96, g1iw, g1ib, g2iw, g2ib, sb,
                                 atb, cons, vbuf);
  wa_gemm2<<<144, 256, 0, stream>>>(g1iw, g2iw, atb, waf, qat, vat);
  prep2<<<336, 256, 0, stream>>>(g1ow, g1ob, g2ow, g2ob, vbuf, cons,
                                 qat, waf, mtab, def, vat, ovt);
  attn_a<<<512, 256, 0, stream>>>(xT, per, mp, mtab, def, zc);
  attn_y<<<256, 256, 0, stream>>>(per, zc, atb, ovt, cons, sb,
                                  g1lg, g1lb, g2lg, g2lb, comb);
  trend_kernel<<<Cn, 256, 0, stream>>>(xT, mp + 1634436L, atb + 84L * 512, sb, comb);
  gemm1_part<<<512, 256, 0, stream>>>(comb, fw1, hbuf, hbu2);
  gemm2_fused<<<256, 256, 0, stream>>>(hbuf, hbu2, fb1, fw2, fb2, out);
}

// Round 11
// 457.934 us; speedup vs baseline: 1.0831x; 1.0831x over previous
//
#include <hip/hip_runtime.h>
#include <math.h>

#define Bn 16
#define Tn 384
#define Cn 128

// ---------------- workspace layout (floats) ----------------
static constexpr long OFF_XT   = 0;
static constexpr long OFF_AVG  = 786432;
static constexpr long OFF_PER  = 835584;
static constexpr long OFF_MP   = 835840;
static constexpr long OFF_AT   = 2507140;
static constexpr long OFF_WAF  = 2605444;
static constexpr long OFF_QAT  = 3195268;
static constexpr long OFF_VAT  = 3391876;
static constexpr long OFF_OVT  = 3588484;
static constexpr long OFF_CON  = 4374916;
static constexpr long OFF_VB   = 4377988;
static constexpr long OFF_MT   = 4379012;
static constexpr long OFF_DEF  = 4673924;
static constexpr long OFF_ZC   = 4677004;
static constexpr long OFF_COMB = 6643084;
static constexpr long OFF_H    = 9788812;
static constexpr long OFF_H2   = 10837388;
static constexpr long WS_FLOATS = 11885964; // ~47.5 MB

__host__ __device__ inline int nanch(int p) {
  if (p == 384) return 96;
  return (p <= 18) ? 12 : (p <= 36) ? 24 : (p <= 72) ? 48 : 96;
}
__host__ __device__ inline int apre(int n) {
  return (n == 12) ? 0 : (n == 24) ? 12 : (n == 48) ? 36 : 84;
}
__host__ __device__ inline long mpoff(int p) {
  if (p == 384) return 1634436L;
  long T = (long)(p - 1) * p / 2;
  if (p <= 18) return 12 * (T - 6);
  if (p <= 36) return 1980 + 24 * (T - 171);
  if (p <= 72) return 13860 + 48 * (T - 666);
  return 108036 + 96 * (T - 2628);
}

__device__ inline void irow(int j, int newl, int oldl, int& i0, int& i1, float& w) {
  double src = ((double)j + 0.5) * (double)oldl / (double)newl - 0.5;
  if (src < 0.0) src = 0.0;
  double mx = (double)(oldl - 1);
  if (src > mx) src = mx;
  int a = (int)src;
  if (a > oldl - 1) a = oldl - 1;
  i0 = a;
  i1 = (a + 1 < oldl) ? (a + 1) : (oldl - 1);
  w = (float)(src - (double)a);
}

// ---------------- stage 0: transpose x -> xT[c][b][t] ----------------
__global__ __launch_bounds__(256) void transpose_kernel(const float* __restrict__ x,
                                                        float* __restrict__ xT) {
  __shared__ float tile[32 * 129];
  int bid = blockIdx.x;
  int b = bid / 12, t0 = (bid % 12) * 32;
  int tid = threadIdx.x;
  for (int i = tid; i < 32 * 128; i += 256) {
    int tt = i >> 7, cc = i & 127;
    tile[tt * 129 + cc] = x[((long)b * Tn + t0 + tt) * Cn + cc];
  }
  __syncthreads();
  for (int i = tid; i < 32 * 128; i += 256) {
    int cc = i >> 5, tt = i & 31;
    xT[((long)cc * Bn + b) * Tn + t0 + tt] = tile[tt * 129 + cc];
  }
}

// ---------------- stage A1: ACF (writes avg[c][t]) ----------------
__global__ __launch_bounds__(256) void acf_kernel(const float* __restrict__ xT,
                                                  float* __restrict__ avg) {
  __shared__ float xb[Bn * 397];
  __shared__ float mean[Bn];
  int bid = blockIdx.x;
  int c = bid / 6, tile = bid % 6;
  int tid = threadIdx.x;
  for (int i = tid; i < Bn * Tn; i += 256) {
    int b = i / Tn, t = i - b * Tn;
    xb[b * 397 + t] = xT[(long)c * Bn * Tn + i];
  }
  for (int i = tid; i < Bn * 13; i += 256) {
    int b = i / 13, t = Tn + (i - b * 13);
    xb[b * 397 + t] = 0.f;
  }
  __syncthreads();
  if (tid < Bn) {
    float s = 0.f;
    for (int t = 0; t < Tn; ++t) s += xb[tid * 397 + t];
    mean[tid] = s / (float)Tn;
  }
  __syncthreads();
  for (int i = tid; i < Bn * Tn; i += 256) {
    int b = i / Tn, t = i - b * Tn;
    xb[b * 397 + t] -= mean[b];
  }
  __syncthreads();
  int q = tid >> 4;
  int g = tid & 15;
  int tau0 = tile * 64 + q * 4;
  const float* xr = xb + g * 397;
  float a0 = 0.f, a1 = 0.f, a2 = 0.f, a3 = 0.f;
  float w0 = xr[tau0], w1 = xr[tau0 + 1], w2 = xr[tau0 + 2], w3 = xr[tau0 + 3];
  int tmax = Tn - tau0;
  for (int t = 0; t < tmax; ++t) {
    float a = xr[t];
    float wn = xr[t + tau0 + 4];
    a0 += a * w0; a1 += a * w1; a2 += a * w2; a3 += a * w3;
    w0 = w1; w1 = w2; w2 = w3; w3 = wn;
  }
  for (int off = 8; off > 0; off >>= 1) {
    a0 += __shfl_down(a0, off, 16);
    a1 += __shfl_down(a1, off, 16);
    a2 += __shfl_down(a2, off, 16);
    a3 += __shfl_down(a3, off, 16);
  }
  if (g == 0) {
    float* dst = avg + (long)c * Tn + tau0;
    dst[0] = a0; dst[1] = a1; dst[2] = a2; dst[3] = a3;
  }
}

// ---------------- stage A2: peaks ----------------
__global__ __launch_bounds__(256) void periods_kernel(const float* __restrict__ avg,
                                                      int* __restrict__ per) {
  int wv = threadIdx.x >> 6;
  int lane = threadIdx.x & 63;
  int c = blockIdx.x * 4 + wv;
  const float* a = avg + (long)c * Tn;
  const float NEG = -1e30f;
  float b1v = NEG, b2v = NEG;
  int b1i = 0, b2i = 0;
  int t0 = 4 + lane * 6;
#pragma unroll
  for (int i = 0; i < 6; ++i) {
    int t = t0 + i;
    if (t > Tn - 1) break;
    float v = a[t];
    float pv = (t == 4) ? NEG : a[t - 1];
    float nv = (t == Tn - 1) ? NEG : a[t + 1];
    bool peak = (v > pv) && (v > nv) && (v > 0.f);
    float m = peak ? v : NEG;
    if (m > b1v || (m == b1v && t < b1i)) {
      b2v = b1v; b2i = b1i; b1v = m; b1i = t;
    } else if (m > b2v || (m == b2v && t < b2i)) {
      b2v = m; b2i = t;
    }
  }
  for (int off = 32; off > 0; off >>= 1) {
    float c1v = __shfl_down(b1v, off, 64); int c1i = __shfl_down(b1i, off, 64);
    float c2v = __shfl_down(b2v, off, 64); int c2i = __shfl_down(b2i, off, 64);
    if (c1v > b1v || (c1v == b1v && c1i < b1i)) {
      b2v = b1v; b2i = b1i; b1v = c1v; b1i = c1i;
    } else if (c1v > b2v || (c1v == b2v && c1i < b2i)) {
      b2v = c1v; b2i = c1i;
    }
    if (c2v > b1v || (c2v == b1v && c2i < b1i)) {
      b2v = b1v; b2i = b1i; b1v = c2v; b1i = c2i;
    } else if (c2v > b2v || (c2v == b2v && c2i < b2i)) {
      b2v = c2v; b2i = c2i;
    }
  }
  if (lane == 0) {
    per[c * 2 + 0] = min(max(b1i, 4), 192);
    per[c * 2 + 1] = min(max(b2i, 4), 192);
  }
}

// ---------------- stage C: Mpinv via tridiagonal Thomas ----------------
__global__ __launch_bounds__(256) void build_mpinv_kernel(const int* __restrict__ per,
                                                          float* __restrict__ mp) {
  __shared__ int ii[384];
  __shared__ float ww[384];
  __shared__ float dd_[96], ee[96], cp[96], idt[96];
  __shared__ float ginv[96 * 97];
  __shared__ float outp[96 * 97];
  __shared__ int flag;
  int tid = threadIdx.x;
  int p = (blockIdx.x < 189) ? (4 + (int)blockIdx.x) : 384;
  if (tid == 0) flag = (p == 384) ? 1 : 0;
  __syncthreads();
  if (p != 384) {
    for (int i = tid; i < Cn * 2; i += 256)
      if (per[i] == p) flag = 1;
  }
  __syncthreads();
  if (!flag) return;

  int n = nanch(p);
  int m = (p >= n) ? n : p;
  float* dst = mp + mpoff(p);

  for (int j = tid; j < p; j += 256) {
    int i0, i1; float w;
    irow(j, p, n, i0, i1, w);
    ii[j] = i0; ww[j] = w;
  }
  for (int i = tid; i < m; i += 256) { dd_[i] = 0.f; ee[i] = 0.f; }
  __syncthreads();

  if (p >= n) {
    for (int j = tid; j < p; j += 256) {
      int i0 = ii[j]; float w = ww[j];
      int i1 = min(i0 + 1, n - 1);
      if (i1 == i0) {
        atomicAdd(&dd_[i0], 1.0f);
      } else {
        float a = 1.f - w, b = w;
        atomicAdd(&dd_[i0], a * a);
        atomicAdd(&dd_[i1], b * b);
        atomicAdd(&ee[i0], a * b);
      }
    }
  } else {
    for (int r = tid; r < p; r += 256) {
      int i0 = ii[r]; float w = ww[r];
      int i1 = min(i0 + 1, n - 1);
      float a, b; int c0 = i0, c1 = i1;
      if (i1 == i0) { a = 1.f; b = 0.f; c1 = -1; }
      else { a = 1.f - w; b = w; }
      dd_[r] = a * a + b * b;
      if (r < p - 1) {
        int j0 = ii[r + 1]; float w2 = ww[r + 1];
        int j1 = min(j0 + 1, n - 1);
        float a2, b2; int d0 = j0, d1 = j1;
        if (j1 == j0) { a2 = 1.f; b2 = 0.f; d1 = -2; }
        else { a2 = 1.f - w2; b2 = w2; }
        float s = 0.f;
        if (c0 == d0) s += a * a2;
        if (c0 == d1) s += a * b2;
        if (c1 == d0) s += b * a2;
        if (c1 == d1) s += b * b2;
        ee[r] = s;
      }
    }
  }
  __syncthreads();
  if (tid == 0) {
    float dt = dd_[0];
    idt[0] = 1.f / dt;
    for (int i = 1; i < m; ++i) {
      float c = ee[i - 1] * idt[i - 1];
      cp[i - 1] = c;
      dt = dd_[i] - ee[i - 1] * c;
      idt[i] = 1.f / dt;
    }
  }
  __syncthreads();
  if (tid < m) {
    int j = tid;
    float z = 1.f;
    ginv[j * 97 + j] = 1.f;
    for (int i = j + 1; i < m; ++i) {
      z = -cp[i - 1] * z;
      ginv[i * 97 + j] = z;
    }
    float xn = ginv[(m - 1) * 97 + j] * idt[m - 1];
    ginv[(m - 1) * 97 + j] = xn;
    for (int i = m - 2; i >= 0; --i) {
      float zi = (i >= j) ? ginv[i * 97 + j] : 0.f;
      xn = zi * idt[i] - cp[i] * xn;
      ginv[i * 97 + j] = xn;
    }
  }
  __syncthreads();
  if (p >= n) {
    for (int idx = tid; idx < p * n; idx += 256) {
      int t = idx / n, k = idx - t * n;
      int i0 = ii[t]; float w = ww[t];
      int i1 = min(i0 + 1, n - 1);
      dst[idx] = (1.f - w) * ginv[i0 * 97 + k] + w * ginv[i1 * 97 + k];
    }
  } else {
    for (int t = tid; t < p; t += 256) {
      for (int k = 0; k < n; ++k) outp[t * 97 + k] = 0.f;
      for (int j = 0; j < p; ++j) {
        float hv = ginv[t * 97 + j];
        int i0 = ii[j]; float w = ww[j];
        int i1 = min(i0 + 1, n - 1);
        outp[t * 97 + i0] += hv * (1.f - w);
        outp[t * 97 + i1] += hv * w;
      }
    }
    __syncthreads();
    for (int idx = tid; idx < p * n; idx += 256) {
      int t = idx / n, k = idx - t * n;
      dst[idx] = outp[t * 97 + k];
    }
  }
}

// ---------------- prep1: anchors^T + constsA merged ----------------
__device__ void at_body(int bid, const float* __restrict__ a12,
                        const float* __restrict__ a24, const float* __restrict__ a48,
                        const float* __restrict__ a96, float* __restrict__ at_tab,
                        float* tile) {
  int a = bid >> 3, d0 = (bid & 7) * 64;
  int n = (a == 0) ? 12 : (a == 1) ? 24 : (a == 2) ? 48 : 96;
  const float* src = (a == 0) ? a12 : (a == 1) ? a24 : (a == 2) ? a48 : a96;
  float* dst = at_tab + (long)apre(n) * 512;
  int tid = threadIdx.x;
  for (int i = tid; i < 64 * n; i += 256) {
    int dd = i / n, k = i - dd * n;
    tile[dd * 97 + k] = src[(long)(d0 + dd) * n + (long)k];
  }
  __syncthreads();
  for (int i = tid; i < n * 64; i += 256) {
    int k = i >> 6, dd = i & 63;
    dst[(long)k * 512 + d0 + dd] = tile[dd * 97 + k];
  }
  if (bid == 0) {
    for (int i = tid; i < 12 * 512; i += 256) at_tab[180L * 512 + i] = 0.f;
  }
}

__device__ void constsA_body(int bid, const float* __restrict__ i1w,
                             const float* __restrict__ i1b, const float* __restrict__ i2w,
                             const float* __restrict__ i2b, const float* __restrict__ sb,
                             float* __restrict__ cons, float* __restrict__ vbuf,
                             float* sv) {
  int s = bid / 96, r0 = (bid % 96) * 16;
  const float* inw = s ? i2w : i1w;
  const float* inb = s ? i2b : i1b;
  int tid = threadIdx.x;
  for (int i = tid; i < 512; i += 256) sv[i] = sb[i];
  __syncthreads();
  int lane = tid & 63, w = tid >> 6;
  for (int rr = 0; rr < 4; ++rr) {
    int r = r0 + w * 4 + rr;
    const float* row = inw + (long)r * 512;
    float part = 0.f;
    for (int kk = 0; kk < 8; ++kk) part += row[lane + 64 * kk] * sv[lane + 64 * kk];
    for (int off = 32; off > 0; off >>= 1) part += __shfl_down(part, off, 64);
    if (lane == 0) {
      float v = part + inb[r];
      if (r < 1024) cons[s * 1536 + r] = v;
      else vbuf[s * 512 + (r - 1024)] = v;
    }
  }
}

__global__ __launch_bounds__(256) void prep1(const float* __restrict__ a12,
                                             const float* __restrict__ a24,
                                             const float* __restrict__ a48,
                                             const float* __restrict__ a96,
                                             const float* __restrict__ i1w,
                                             const float* __restrict__ i1b,
                                             const float* __restrict__ i2w,
                                             const float* __restrict__ i2b,
                                             const float* __restrict__ sb,
                                             float* __restrict__ at_tab,
                                             float* __restrict__ cons,
                                             float* __restrict__ vbuf) {
  __shared__ float sm[64 * 97];
  int bid = blockIdx.x;
  if (bid < 32) at_body(bid, a12, a24, a48, a96, at_tab, sm);
  else constsA_body(bid - 32, i1w, i1b, i2w, i2b, sb, cons, vbuf, sm);
}

// ---------------- stage P2: WAfull = in_w @ A_cat ----------------
__global__ __launch_bounds__(256) void wa_gemm2(const float* __restrict__ iw0,
                                                const float* __restrict__ iw1,
                                                const float* __restrict__ atb,
                                                float* __restrict__ waf,
                                                float* __restrict__ qat,
                                                float* __restrict__ vat) {
  __shared__ float smem[2 * 32 * 68];
  float* As = smem;
  float* Ws = smem + 32 * 68;
  int bid = blockIdx.x;
  int s = bid / 72, r = bid % 72;
  int m0 = (r / 3) * 64, n0 = (r % 3) * 64;
  const float* A = s ? iw1 : iw0;
  float* wafs = waf + (long)s * 294912;
  int tid = threadIdx.x;
  int tm = tid & 15, tn = tid >> 4;
  float acc[4][4];
#pragma unroll
  for (int i = 0; i < 4; ++i)
#pragma unroll
    for (int j = 0; j < 4; ++j) acc[i][j] = 0.f;
  int row = tid >> 3, kc = (tid & 7) * 4;
  for (int k0 = 0; k0 < 512; k0 += 32) {
    float4 v = *(const float4*)&A[(long)(m0 + row) * 512 + k0 + kc];
    As[(kc + 0) * 68 + row] = v.x; As[(kc + 1) * 68 + row] = v.y;
    As[(kc + 2) * 68 + row] = v.z; As[(kc + 3) * 68 + row] = v.w;
    v = *(const float4*)&A[(long)(m0 + row + 32) * 512 + k0 + kc];
    As[(kc + 0) * 68 + row + 32] = v.x; As[(kc + 1) * 68 + row + 32] = v.y;
    As[(kc + 2) * 68 + row + 32] = v.z; As[(kc + 3) * 68 + row + 32] = v.w;
    v = *(const float4*)&atb[(long)(n0 + row) * 512 + k0 + kc];
    Ws[(kc + 0) * 68 + row] = v.x; Ws[(kc + 1) * 68 + row] = v.y;
    Ws[(kc + 2) * 68 + row] = v.z; Ws[(kc + 3) * 68 + row] = v.w;
    v = *(const float4*)&atb[(long)(n0 + row + 32) * 512 + k0 + kc];
    Ws[(kc + 0) * 68 + row + 32] = v.x; Ws[(kc + 1) * 68 + row + 32] = v.y;
    Ws[(kc + 2) * 68 + row + 32] = v.z; Ws[(kc + 3) * 68 + row + 32] = v.w;
    __syncthreads();
    for (int kk = 0; kk < 32; ++kk) {
      float4 a = *(const float4*)&As[kk * 68 + tm * 4];
      float4 w = *(const float4*)&Ws[kk * 68 + tn * 4];
      acc[0][0] += a.x * w.x; acc[0][1] += a.x * w.y; acc[0][2] += a.x * w.z; acc[0][3] += a.x * w.w;
      acc[1][0] += a.y * w.x; acc[1][1] += a.y * w.y; acc[1][2] += a.y * w.z; acc[1][3] += a.y * w.w;
      acc[2][0] += a.z * w.x; acc[2][1] += a.z * w.y; acc[2][2] += a.z * w.z; acc[2][3] += a.z * w.w;
      acc[3][0] += a.w * w.x; acc[3][1] += a.w * w.y; acc[3][2] += a.w * w.z; acc[3][3] += a.w * w.w;
    }
    __syncthreads();
  }
#pragma unroll
  for (int mi = 0; mi < 4; ++mi) {
    float4 o;
    o.x = acc[mi][0]; o.y = acc[mi][1]; o.z = acc[mi][2]; o.w = acc[mi][3];
    *(float4*)&wafs[(long)(m0 + tm * 4 + mi) * 192 + n0 + tn * 4] = o;
  }
  if (m0 < 512 || m0 >= 1024) {
    float* Ct = smem;
#pragma unroll
    for (int mi = 0; mi < 4; ++mi)
#pragma unroll
      for (int j = 0; j < 4; ++j)
        Ct[(tn * 4 + j) * 65 + tm * 4 + mi] = acc[mi][j];
    __syncthreads();
    float* dst = ((m0 < 512) ? qat : vat) + (long)s * 98304;
    int mr = m0 & 511;
    for (int i = tid; i < 64 * 64; i += 256) {
      int cc = i >> 6, rr = i & 63;
      dst[(long)(n0 + cc) * 512 + mr + rr] = Ct[cc * 65 + rr];
    }
  }
}

// ---------------- prep2 bodies ----------------
__device__ void constsB_body(int bid, const float* __restrict__ o1w,
                             const float* __restrict__ o1b, const float* __restrict__ o2w,
                             const float* __restrict__ o2b, const float* __restrict__ vbuf,
                             float* __restrict__ cons, float* vv) {
  int s = bid / 32, r0 = (bid % 32) * 16;
  const float* outw = s ? o2w : o1w;
  const float* outb = s ? o2b : o1b;
  int tid = threadIdx.x;
  for (int i = tid; i < 512; i += 256) vv[i] = vbuf[s * 512 + i];
  __syncthreads();
  int lane = tid & 63, w = tid >> 6;
  for (int rr = 0; rr < 4; ++rr) {
    int r = r0 + w * 4 + rr;
    const float* row = outw + (long)r * 512;
    float part = 0.f;
    for (int kk = 0; kk < 8; ++kk) part += row[lane + 64 * kk] * vv[lane + 64 * kk];
    for (int off = 32; off > 0; off >>= 1) part += __shfl_down(part, off, 64);
    if (lane == 0) cons[s * 1536 + 1024 + r] = part + outb[r];
  }
}

__device__ void mt_body(int bid, const float* __restrict__ qat,
                        const float* __restrict__ waf, float* __restrict__ mt,
                        float* As, float* Ws) {
  int s4h = bid / 9, t = bid % 9;
  int s = s4h >> 2, h = s4h & 3;
  int m0 = (t / 3) * 64, n0 = (t % 3) * 64;
  const float* A = qat + (long)s * 98304 + h * 128;
  const float* B = waf + (long)s * 294912 + 98304 + (long)(h * 128) * 192;
  float* C = mt + (long)s4h * 36864;
  int tid = threadIdx.x;
  int tm = tid & 15, tn = tid >> 4;
  float acc[4][4];
#pragma unroll
  for (int i = 0; i < 4; ++i)
#pragma unroll
    for (int j = 0; j < 4; ++j) acc[i][j] = 0.f;
  int row = tid >> 3, kc = (tid & 7) * 4;
  for (int k0 = 0; k0 < 128; k0 += 32) {
    float4 v = *(const float4*)&A[(long)(m0 + row) * 512 + k0 + kc];
    As[(kc + 0) * 68 + row] = v.x; As[(kc + 1) * 68 + row] = v.y;
    As[(kc + 2) * 68 + row] = v.z; As[(kc + 3) * 68 + row] = v.w;
    v = *(const float4*)&A[(long)(m0 + row + 32) * 512 + k0 + kc];
    As[(kc + 0) * 68 + row + 32] = v.x; As[(kc + 1) * 68 + row + 32] = v.y;
    As[(kc + 2) * 68 + row + 32] = v.z; As[(kc + 3) * 68 + row + 32] = v.w;
    for (int l = tid; l < 512; l += 256) {
      int i = l >> 4, kq = (l & 15) * 4;
      float4 b = *(const float4*)&B[(long)(k0 + i) * 192 + n0 + kq];
      Ws[i * 68 + kq + 0] = b.x; Ws[i * 68 + kq + 1] = b.y;
      Ws[i * 68 + kq + 2] = b.z; Ws[i * 68 + kq + 3] = b.w;
    }
    __syncthreads();
    for (int kk = 0; kk < 32; ++kk) {
      float4 a = *(const float4*)&As[kk * 68 + tm * 4];
      float4 w = *(const float4*)&Ws[kk * 68 + tn * 4];
      acc[0][0] += a.x * w.x; acc[0][1] += a.x * w.y; acc[0][2] += a.x * w.z; acc[0][3] += a.x * w.w;
      acc[1][0] += a.y * w.x; acc[1][1] += a.y * w.y; acc[1][2] += a.y * w.z; acc[1][3] += a.y * w.w;
      acc[2][0] += a.z * w.x; acc[2][1] += a.z * w.y; acc[2][2] += a.z * w.z; acc[2][3] += a.z * w.w;
      acc[3][0] += a.w * w.x; acc[3][1] += a.w * w.y; acc[3][2] += a.w * w.z; acc[3][3] += a.w * w.w;
    }
    __syncthreads();
  }
#pragma unroll
  for (int mi = 0; mi < 4; ++mi) {
    float4 o;
    o.x = acc[mi][0]; o.y = acc[mi][1]; o.z = acc[mi][2]; o.w = acc[mi][3];
    *(float4*)&C[(long)(m0 + tm * 4 + mi) * 192 + n0 + tn * 4] = o;
  }
}

__device__ void sc_body(int bid, const float* __restrict__ qat,
                        const float* __restrict__ waf, const float* __restrict__ cons,
                        float* __restrict__ def, float* qcl, float* kbl) {
  int s = bid >> 2, h = bid & 3;
  int tid = threadIdx.x;
  const float* qc = cons + s * 1536;
  const float* kb = qc + 512;
  if (tid < 128) {
    qcl[tid] = qc[h * 128 + tid];
    kbl[tid] = kb[h * 128 + tid];
  }
  __syncthreads();
  const float* katb = waf + (long)s * 294912 + 98304;
  const float* qats = qat + (long)s * 98304;
  float* dtab = def + (long)(s * 4 + h) * 192;
  float* etab = def + 1536 + (long)(s * 4 + h) * 192;
  float* ftab = def + 3072 + (s * 4 + h);
  if (tid < 192) {
    float acc = 0.f;
    for (int i = 0; i < 128; ++i) acc += katb[(long)(h * 128 + i) * 192 + tid] * qcl[i];
    dtab[tid] = acc;
    float acc2 = 0.f;
    const float* qr = qats + (long)tid * 512 + h * 128;
    for (int i = 0; i < 128; ++i) acc2 += qr[i] * kbl[i];
    etab[tid] = acc2;
  }
  if (tid < 64) {
    float acc = 0.f;
    for (int i = tid; i < 128; i += 64) acc += qcl[i] * kbl[i];
    for (int off = 32; off > 0; off >>= 1) acc += __shfl_down(acc, off, 64);
    if (tid == 0) *ftab = acc;
  }
}

__device__ void ova_body(int bid, const float* __restrict__ ow0,
                         const float* __restrict__ ow1, const float* __restrict__ vat,
                         float* __restrict__ ovt, float* As, float* Ws) {
  int s = bid / 96, r = bid % 96;
  int h = r / 24, r2 = r % 24;
  int m0 = (r2 / 8) * 64, n0 = (r2 % 8) * 64;
  const float* A = vat + (long)s * 98304 + h * 128;
  const float* W = (s ? ow1 : ow0) + h * 128;
  float* C = ovt + ((long)(s * 4 + h) * 192) * 512;
  int tid = threadIdx.x;
  int tm = tid & 15, tn = tid >> 4;
  float acc[4][4];
#pragma unroll
  for (int i = 0; i < 4; ++i)
#pragma unroll
    for (int j = 0; j < 4; ++j) acc[i][j] = 0.f;
  int row = tid >> 3, kc = (tid & 7) * 4;
  for (int k0 = 0; k0 < 128; k0 += 32) {
    float4 v = *(const float4*)&A[(long)(m0 + row) * 512 + k0 + kc];
    As[(kc + 0) * 68 + row] = v.x; As[(kc + 1) * 68 + row] = v.y;
    As[(kc + 2) * 68 + row] = v.z; As[(kc + 3) * 68 + row] = v.w;
    v = *(const float4*)&A[(long)(m0 + row + 32) * 512 + k0 + kc];
    As[(kc + 0) * 68 + row + 32] = v.x; As[(kc + 1) * 68 + row + 32] = v.y;
    As[(kc + 2) * 68 + row + 32] = v.z; As[(kc + 3) * 68 + row + 32] = v.w;
    v = *(const float4*)&W[(long)(n0 + row) * 512 + k0 + kc];
    Ws[(kc + 0) * 68 + row] = v.x; Ws[(kc + 1) * 68 + row] = v.y;
    Ws[(kc + 2) * 68 + row] = v.z; Ws[(kc + 3) * 68 + row] = v.w;
    v = *(const float4*)&W[(long)(n0 + row + 32) * 512 + k0 + kc];
    Ws[(kc + 0) * 68 + row + 32] = v.x; Ws[(kc + 1) * 68 + row + 32] = v.y;
    Ws[(kc + 2) * 68 + row + 32] = v.z; Ws[(kc + 3) * 68 + row + 32] = v.w;
    __syncthreads();
    for (int kk = 0; kk < 32; ++kk) {
      float4 a = *(const float4*)&As[kk * 68 + tm * 4];
      float4 w = *(const float4*)&Ws[kk * 68 + tn * 4];
      acc[0][0] += a.x * w.x; acc[0][1] += a.x * w.y; acc[0][2] += a.x * w.z; acc[0][3] += a.x * w.w;
      acc[1][0] += a.y * w.x; acc[1][1] += a.y * w.y; acc[1][2] += a.y * w.z; acc[1][3] += a.y * w.w;
      acc[2][0] += a.z * w.x; acc[2][1] += a.z * w.y; acc[2][2] += a.z * w.z; acc[2][3] += a.z * w.w;
      acc[3][0] += a.w * w.x; acc[3][1] += a.w * w.y; acc[3][2] += a.w * w.z; acc[3][3] += a.w * w.w;
    }
    __syncthreads();
  }
#pragma unroll
  for (int mi = 0; mi < 4; ++mi) {
    float4 o;
    o.x = acc[mi][0]; o.y = acc[mi][1]; o.z = acc[mi][2]; o.w = acc[mi][3];
    *(float4*)&C[(long)(m0 + tm * 4 + mi) * 512 + n0 + tn * 4] = o;
  }
}

__global__ __launch_bounds__(256) void prep2(const float* __restrict__ o1w,
                                             const float* __restrict__ o1b,
                                             const float* __restrict__ o2w,
                                             const float* __restrict__ o2b,
                                             const float* __restrict__ vbuf,
                                             float* __restrict__ cons,
                                             const float* __restrict__ qat,
                                             const float* __restrict__ waf,
                                             float* __restrict__ mtab,
                                             float* __restrict__ def,
                                             const float* __restrict__ vat,
                                             float* __restrict__ ovt) {
  __shared__ float sm[2 * 32 * 68];
  int bid = blockIdx.x;
  if (bid < 64) constsB_body(bid, o1w, o1b, o2w, o2b, vbuf, cons, sm);
  else if (bid < 136) mt_body(bid - 64, qat, waf, mtab, sm, sm + 32 * 68);
  else if (bid < 144) sc_body(bid - 136, qat, waf, cons, def, sm, sm + 128);
  else ova_body(bid - 144, o1w, o2w, vat, ovt, sm, sm + 32 * 68);
}

// ---------------- stage B1: attn_a — Z, scores, softmax, zh -> zcat ----------------
__global__ __launch_bounds__(256) void attn_a(
    const float* __restrict__ xT, const int* __restrict__ per,
    const float* __restrict__ mp, const float* __restrict__ mt,
    const float* __restrict__ def, float* __restrict__ zc) {
  __shared__ float xb[8 * 384];
  __shared__ float Z[8 * 1248];
  __shared__ float zl[8 * 96];
  __shared__ float arb[8 * 384];
  __shared__ float qkc[32];
  float* scp = xb;

  int tid = threadIdx.x;
  int bid = blockIdx.x;
  int slot = bid & 1;
  int c = (bid >> 1) & 127;
  int b0 = (bid >> 8) * 8;
  int p = per[c * 2 + slot];
  int n = nanch(p);
  int np = Tn / p;
  int n1 = n + 1;
  float s = sqrtf((float)p / (float)n);
  float s2 = s * s;
  const float rscale = 0.08838834764831845f;
  int pre = apre(n);
  const float* mpp = mp + mpoff(p);
  const float* dt = def + (long)(slot * 4) * 192;
  const float* et = def + 1536 + (long)(slot * 4) * 192;
  const float* ft = def + 3072 + slot * 4;
  const float* mtb = mt + (long)(slot * 4) * 36864;

  for (int g = 0; g < 8; ++g)
    for (int t = tid; t < Tn; t += 256)
      xb[g * 384 + t] = xT[((long)c * Bn + b0 + g) * Tn + t];
  __syncthreads();

  // Ph1: Z = patches @ Mpinv (8-way g-fused, k-pairs, float2 Mpinv loads)
  {
    int half = n >> 1;
    int tot1 = np * half;
    for (int idx = tid; idx < tot1; idx += 256) {
      int j = idx / half, k2 = idx - j * half;
      int k = k2 * 2;
      int jb = j * p;
      const float* mk = mpp + k;
      float a0[8], a1[8];
#pragma unroll
      for (int g = 0; g < 8; ++g) { a0[g] = 0.f; a1[g] = 0.f; }
      for (int t = 0; t < p; ++t) {
        float2 m = *(const float2*)&mk[(long)t * n];
#pragma unroll
        for (int g = 0; g < 8; ++g) {
          float xv = xb[g * 384 + jb + t];
          a0[g] += m.x * xv;
          a1[g] += m.y * xv;
        }
      }
      int zi = j * n1 + k;
#pragma unroll
      for (int g = 0; g < 8; ++g) {
        Z[g * 1248 + zi] = a0[g];
        Z[g * 1248 + zi + 1] = a1[g];
      }
    }
  }
  __syncthreads();

  for (int idx = tid; idx < 8 * n; idx += 256) {
    int g = idx / n, k = idx - g * n;
    zl[g * 96 + k] = Z[g * 1248 + (np - 1) * n1 + k];
  }
  __syncthreads();

  {
    int pair = tid >> 3, l = tid & 7;
    int g = pair >> 2, h = pair & 3;
    const float* eh = et + h * 192 + pre;
    float acc = 0.f;
    for (int j = l; j < n; j += 8) acc += eh[j] * zl[g * 96 + j];
    for (int off = 4; off > 0; off >>= 1) acc += __shfl_down(acc, off, 8);
    if (l == 0) qkc[g * 4 + h] = s * acc + ft[h];
  }
  {
    int tot = 4 * n;
    for (int idx = tid; idx < tot; idx += 256) {
      int h = idx / n, k = idx - h * n;
      const float* mtc = mtb + (long)h * 36864 + (long)pre * 192 + pre + k;
      float a[8];
#pragma unroll
      for (int g = 0; g < 8; ++g) a[g] = 0.f;
      for (int j0 = 0; j0 < n; j0 += 4) {
        float4 zb[8];
#pragma unroll
        for (int g = 0; g < 8; ++g) zb[g] = *(const float4*)&zl[g * 96 + j0];
#pragma unroll
        for (int c4 = 0; c4 < 4; ++c4) {
          float mv = mtc[(long)(j0 + c4) * 192];
#pragma unroll
          for (int g = 0; g < 8; ++g) {
            float zv = (c4 == 0) ? zb[g].x : (c4 == 1) ? zb[g].y : (c4 == 2) ? zb[g].z : zb[g].w;
            a[g] += mv * zv;
          }
        }
      }
      float dv = dt[h * 192 + pre + k];
#pragma unroll
      for (int g = 0; g < 8; ++g) arb[g * 384 + h * 96 + k] = s2 * a[g] + s * dv;
    }
  }
  __syncthreads();

  // scores
  {
    int fnp = 4 * np;
    int tot = 8 * fnp;
    for (int idx = tid; idx < tot; idx += 256) {
      int g = idx / fnp;
      int r = idx - g * fnp;
      int h = r / np, j = r - h * np;
      const float* ap = arb + g * 384 + h * 96;
      const float* zp = Z + g * 1248 + j * n1;
      float acc = 0.f;
      for (int k = 0; k < n; ++k) acc += ap[k] * zp[k];
      scp[g * 384 + h * np + j] = (acc + qkc[g * 4 + h]) * rscale;
    }
  }
  __syncthreads();

  // softmax
  {
    int pair = tid >> 3, l = tid & 7;
    int g = pair >> 2, h = pair & 3;
    float* sp = scp + g * 384 + h * np;
    float m = -1e30f;
    for (int j = l; j < np; j += 8) m = fmaxf(m, sp[j]);
    for (int off = 4; off > 0; off >>= 1) m = fmaxf(m, __shfl_xor(m, off, 8));
    float lsum = 0.f;
    for (int j = l; j < np; j += 8) { float e = expf(sp[j] - m); sp[j] = e; lsum += e; }
    for (int off = 4; off > 0; off >>= 1) lsum += __shfl_xor(lsum, off, 8);
    float il = 1.f / lsum;
    for (int j = l; j < np; j += 8) sp[j] *= il;
  }
  __syncthreads();

  // zh
  {
    int fn = 4 * n;
    int tot = 8 * fn;
    for (int idx = tid; idx < tot; idx += 256) {
      int g = idx / fn;
      int r = idx - g * fn;
      int h = r / n, k = r - h * n;
      const float* sp = scp + g * 384 + h * np;
      const float* zp = Z + g * 1248 + k;
      float acc = 0.f;
      for (int j = 0; j < np; ++j) acc += sp[j] * zp[j * n1];
      arb[g * 384 + h * 96 + k] = acc;
    }
  }
  __syncthreads();

  // write zcat (s-scaled)
  {
    long rowb = ((long)slot * 128 + c) * 16 + b0;
    int fn5 = 5 * n;
    int tot = 8 * fn5;
    for (int idx = tid; idx < tot; idx += 256) {
      int g = idx / fn5, r = idx - g * fn5;
      int seg = r / n, k = r - seg * n;
      float v = (seg == 0) ? zl[g * 96 + k] : arb[g * 384 + (seg - 1) * 96 + k];
      zc[(rowb + g) * 480 + seg * 96 + k] = s * v;
    }
  }
}

// ---------------- stage B2: attn_y ----------------
__global__ __launch_bounds__(256) void attn_y(
    const int* __restrict__ per, const float* __restrict__ zc,
    const float* __restrict__ at_tab, const float* __restrict__ ovt,
    const float* __restrict__ cons, const float* __restrict__ sb,
    const float* __restrict__ l1g, const float* __restrict__ l1b,
    const float* __restrict__ l2g, const float* __restrict__ l2b,
    float* __restrict__ comb) {
  __shared__ float zbuf[16 * 480];
  __shared__ float red[128];
  __shared__ float stats[32];
  int tid = threadIdx.x;
  int bid = blockIdx.x;
  int slot = bid & 1, c = bid >> 1;
  int p = per[c * 2 + slot];
  int n = nanch(p);
  int pre = apre(n);
  const float* atb = at_tab + (long)pre * 512;
  const float* oc = cons + slot * 1536 + 1024;
  const float* lng = slot ? l2g : l1g;
  const float* lnb = slot ? l2b : l1b;
  long rowb = ((long)slot * 128 + c) * 16;
  int fn5 = 5 * n;
  for (int idx = tid; idx < 16 * fn5; idx += 256) {
    int g = idx / fn5, r = idx - g * fn5;
    int seg = r / n, k = r - seg * n;
    zbuf[g * 480 + seg * 96 + k] = zc[(rowb + g) * 480 + seg * 96 + k];
  }
  __syncthreads();
  int d0 = 2 * tid;
  float acc0[16], acc1[16];
#pragma unroll
  for (int r = 0; r < 16; ++r) { acc0[r] = 0.f; acc1[r] = 0.f; }
  for (int seg = 0; seg < 5; ++seg) {
    const float* wt = (seg == 0) ? atb
                                 : (ovt + ((long)(slot * 4 + seg - 1) * 192 + pre) * 512);
    int zoff = seg * 96;
    for (int k0 = 0; k0 < n; k0 += 4) {
      float4 zv[16];
#pragma unroll
      for (int r = 0; r < 16; ++r) zv[r] = *(const float4*)&zbuf[r * 480 + zoff + k0];
#pragma unroll
      for (int c4 = 0; c4 < 4; ++c4) {
        float2 w = *(const float2*)&wt[(long)(k0 + c4) * 512 + d0];
#pragma unroll
        for (int r = 0; r < 16; ++r) {
          float z = (c4 == 0) ? zv[r].x : (c4 == 1) ? zv[r].y : (c4 == 2) ? zv[r].z : zv[r].w;
          acc0[r] += w.x * z;
          acc1[r] += w.y * z;
        }
      }
    }
  }
  float2 sbv = *(const float2*)&sb[d0];
  float2 ocv = *(const float2*)&oc[d0];
  float s0 = sbv.x + ocv.x, s1 = sbv.y + ocv.y;
#pragma unroll
  for (int r = 0; r < 16; ++r) { acc0[r] += s0; acc1[r] += s1; }
  float ps[32];
#pragma unroll
  for (int r = 0; r < 16; ++r) {
    ps[2 * r] = acc0[r] + acc1[r];
    ps[2 * r + 1] = acc0[r] * acc0[r] + acc1[r] * acc1[r];
  }
  int w = tid >> 6, lane = tid & 63;
  for (int off = 32; off > 0; off >>= 1) {
#pragma unroll
    for (int i = 0; i < 32; ++i) ps[i] += __shfl_down(ps[i], off, 64);
  }
  if (lane == 0) {
#pragma unroll
    for (int i = 0; i < 32; ++i) red[w * 32 + i] = ps[i];
  }
  __syncthreads();
  if (tid < 16) {
    int r = tid;
    float ssum = red[2 * r] + red[32 + 2 * r] + red[64 + 2 * r] + red[96 + 2 * r];
    float qsum = red[2 * r + 1] + red[32 + 2 * r + 1] + red[64 + 2 * r + 1] + red[96 + 2 * r + 1];
    float mu = ssum / 512.f;
    float var = qsum / 512.f - mu * mu;
    stats[2 * r] = mu;
    stats[2 * r + 1] = rsqrtf(var + 1e-5f);
  }
  __syncthreads();
  float2 gv = *(const float2*)&lng[d0];
  float2 bv = *(const float2*)&lnb[d0];
#pragma unroll
  for (int r = 0; r < 16; ++r) {
    float mu = stats[2 * r], rstd = stats[2 * r + 1];
    long base = ((long)r * Cn + c) * 1536 + slot * 512;
    float2 o;
    o.x = (acc0[r] - mu) * rstd * gv.x + bv.x;
    o.y = (acc1[r] - mu) * rstd * gv.y + bv.y;
    *(float2*)&comb[base + d0] = o;
  }
}

// ---------------- stage D: trend ----------------
__global__ __launch_bounds__(256) void trend_kernel(const float* __restrict__ xT,
                                                    const float* __restrict__ mp384,
                                                    const float* __restrict__ at96,
                                                    const float* __restrict__ sb,
                                                    float* __restrict__ comb) {
  __shared__ float xb[Bn * Tn];
  __shared__ float Ztr[Bn * 97];
  int c = blockIdx.x, tid = threadIdx.x;
  for (int i = tid; i < Bn * Tn; i += 256) xb[i] = xT[(long)c * Bn * Tn + i];
  __syncthreads();
  for (int idx = tid; idx < 4 * 96; idx += 256) {
    int bq = idx / 96, k = idx - bq * 96;
    const float* x0 = xb + (bq * 4 + 0) * Tn;
    const float* x1 = xb + (bq * 4 + 1) * Tn;
    const float* x2 = xb + (bq * 4 + 2) * Tn;
    const float* x3 = xb + (bq * 4 + 3) * Tn;
    const float* mk = mp384 + k;
    float a0 = 0.f, a1 = 0.f, a2 = 0.f, a3 = 0.f;
    for (int t = 0; t < Tn; ++t) {
      float m = mk[(long)t * 96];
      a0 += m * x0[t]; a1 += m * x1[t]; a2 += m * x2[t]; a3 += m * x3[t];
    }
    Ztr[(bq * 4 + 0) * 97 + k] = a0;
    Ztr[(bq * 4 + 1) * 97 + k] = a1;
    Ztr[(bq * 4 + 2) * 97 + k] = a2;
    Ztr[(bq * 4 + 3) * 97 + k] = a3;
  }
  __syncthreads();
  float acc0[Bn], acc1[Bn];
#pragma unroll
  for (int b = 0; b < Bn; ++b) { acc0[b] = 0.f; acc1[b] = 0.f; }
  for (int k = 0; k < 96; ++k) {
    float w0 = at96[(long)k * 512 + tid];
    float w1 = at96[(long)k * 512 + 256 + tid];
#pragma unroll
    for (int b = 0; b < Bn; ++b) {
      float z = Ztr[b * 97 + k];
      acc0[b] += w0 * z;
      acc1[b] += w1 * z;
    }
  }
  float s0 = sb[tid], s1 = sb[256 + tid];
#pragma unroll
  for (int b = 0; b < Bn; ++b) {
    long base = ((long)b * Cn + c) * 1536 + 1024;
    comb[base + tid] = 2.f * acc0[b] + s0;
    comb[base + 256 + tid] = 2.f * acc1[b] + s1;
  }
}

// ---------------- stage E1: fusion GEMM-1, split-K halves, double-buffered LDS ----------------
__global__ __launch_bounds__(256) void gemm1_part(const float* __restrict__ A,
                                                  const float* __restrict__ W,
                                                  float* __restrict__ C0,
                                                  float* __restrict__ C1) {
  __shared__ float As[2][32 * 68];
  __shared__ float Ws[2][32 * 68];
  int bid = blockIdx.x;
  int kh = bid >> 8;
  int r = bid & 255;
  int m0 = (r >> 3) * 64, n0 = (r & 7) * 64;
  float* C = kh ? C1 : C0;
  const float* Ab = A + kh * 768;
  const float* Wb = W + kh * 768;
  int tid = threadIdx.x;
  int tm = tid & 15, tn = tid >> 4;
  int row = tid >> 3, kc = (tid & 7) * 4;
  float acc[4][4];
#pragma unroll
  for (int i = 0; i < 4; ++i)
#pragma unroll
    for (int j = 0; j < 4; ++j) acc[i][j] = 0.f;
  float4 ra0, ra1, rw0, rw1;
  auto ld = [&](int k0) {
    ra0 = *(const float4*)&Ab[(long)(m0 + row) * 1536 + k0 + kc];
    ra1 = *(const float4*)&Ab[(long)(m0 + row + 32) * 1536 + k0 + kc];
    rw0 = *(const float4*)&Wb[(long)(n0 + row) * 1536 + k0 + kc];
    rw1 = *(const float4*)&Wb[(long)(n0 + row + 32) * 1536 + k0 + kc];
  };
  auto st = [&](int b) {
    float* as = As[b]; float* ws = Ws[b];
    as[(kc + 0) * 68 + row] = ra0.x; as[(kc + 1) * 68 + row] = ra0.y;
    as[(kc + 2) * 68 + row] = ra0.z; as[(kc + 3) * 68 + row] = ra0.w;
    as[(kc + 0) * 68 + row + 32] = ra1.x; as[(kc + 1) * 68 + row + 32] = ra1.y;
    as[(kc + 2) * 68 + row + 32] = ra1.z; as[(kc + 3) * 68 + row + 32] = ra1.w;
    ws[(kc + 0) * 68 + row] = rw0.x; ws[(kc + 1) * 68 + row] = rw0.y;
    ws[(kc + 2) * 68 + row] = rw0.z; ws[(kc + 3) * 68 + row] = rw0.w;
    ws[(kc + 0) * 68 + row + 32] = rw1.x; ws[(kc + 1) * 68 + row + 32] = rw1.y;
    ws[(kc + 2) * 68 + row + 32] = rw1.z; ws[(kc + 3) * 68 + row + 32] = rw1.w;
  };
  ld(0); st(0); __syncthreads();
  ld(32);
  for (int ch = 0; ch < 24; ++ch) {
    int cur = ch & 1;
    const float* as = As[cur];
    const float* ws = Ws[cur];
    for (int kk = 0; kk < 32; ++kk) {
      float4 a = *(const float4*)&as[kk * 68 + tm * 4];
      float4 w = *(const float4*)&ws[kk * 68 + tn * 4];
      acc[0][0] += a.x * w.x; acc[0][1] += a.x * w.y; acc[0][2] += a.x * w.z; acc[0][3] += a.x * w.w;
      acc[1][0] += a.y * w.x; acc[1][1] += a.y * w.y; acc[1][2] += a.y * w.z; acc[1][3] += a.y * w.w;
      acc[2][0] += a.z * w.x; acc[2][1] += a.z * w.y; acc[2][2] += a.z * w.z; acc[2][3] += a.z * w.w;
      acc[3][0] += a.w * w.x; acc[3][1] += a.w * w.y; acc[3][2] += a.w * w.z; acc[3][3] += a.w * w.w;
    }
    __syncthreads();
    if (ch + 1 < 24) {
      st(cur ^ 1);
      if (ch + 2 < 24) ld((ch + 2) * 32);
      __syncthreads();
    }
  }
#pragma unroll
  for (int mi = 0; mi < 4; ++mi) {
    float4 o;
    o.x = acc[mi][0]; o.y = acc[mi][1]; o.z = acc[mi][2]; o.w = acc[mi][3];
    *(float4*)&C[(long)(m0 + tm * 4 + mi) * 512 + n0 + tn * 4] = o;
  }
}

// ---------------- stage E2: GEMM-2, A = gelu(H0+H1+fb1) fused in staging ----------------
__global__ __launch_bounds__(256) void gemm2_fused(const float* __restrict__ H0,
                                                   const float* __restrict__ H1,
                                                   const float* __restrict__ fb1,
                                                   const float* __restrict__ W,
                                                   const float* __restrict__ fb2,
                                                   float* __restrict__ C) {
  __shared__ float As[32 * 68];
  __shared__ float Ws[32 * 68];
  int m0 = (blockIdx.x >> 3) * 64, n0 = (blockIdx.x & 7) * 64;
  int tid = threadIdx.x;
  int tm = tid & 15, tn = tid >> 4;
  float acc[4][4];
#pragma unroll
  for (int i = 0; i < 4; ++i)
#pragma unroll
    for (int j = 0; j < 4; ++j) acc[i][j] = 0.f;
  int row = tid >> 3, kc = (tid & 7) * 4;
  for (int k0 = 0; k0 < 512; k0 += 32) {
    float4 bs = *(const float4*)&fb1[k0 + kc];
    float4 h0 = *(const float4*)&H0[(long)(m0 + row) * 512 + k0 + kc];
    float4 h1 = *(const float4*)&H1[(long)(m0 + row) * 512 + k0 + kc];
    float4 v;
    v.x = h0.x + h1.x + bs.x; v.y = h0.y + h1.y + bs.y;
    v.z = h0.z + h1.z + bs.z; v.w = h0.w + h1.w + bs.w;
    v.x = 0.5f * v.x * (1.f + erff(v.x * 0.7071067811865475f));
    v.y = 0.5f * v.y * (1.f + erff(v.y * 0.7071067811865475f));
    v.z = 0.5f * v.z * (1.f + erff(v.z * 0.7071067811865475f));
    v.w = 0.5f * v.w * (1.f + erff(v.w * 0.7071067811865475f));
    As[(kc + 0) * 68 + row] = v.x; As[(kc + 1) * 68 + row] = v.y;
    As[(kc + 2) * 68 + row] = v.z; As[(kc + 3) * 68 + row] = v.w;
    h0 = *(const float4*)&H0[(long)(m0 + row + 32) * 512 + k0 + kc];
    h1 = *(const float4*)&H1[(long)(m0 + row + 32) * 512 + k0 + kc];
    v.x = h0.x + h1.x + bs.x; v.y = h0.y + h1.y + bs.y;
    v.z = h0.z + h1.z + bs.z; v.w = h0.w + h1.w + bs.w;
    v.x = 0.5f * v.x * (1.f + erff(v.x * 0.7071067811865475f));
    v.y = 0.5f * v.y * (1.f + erff(v.y * 0.7071067811865475f));
    v.z = 0.5f * v.z * (1.f + erff(v.z * 0.7071067811865475f));
    v.w = 0.5f * v.w * (1.f + erff(v.w * 0.7071067811865475f));
    As[(kc + 0) * 68 + row + 32] = v.x; As[(kc + 1) * 68 + row + 32] = v.y;
    As[(kc + 2) * 68 + row + 32] = v.z; As[(kc + 3) * 68 + row + 32] = v.w;
    float4 wv = *(const float4*)&W[(long)(n0 + row) * 512 + k0 + kc];
    Ws[(kc + 0) * 68 + row] = wv.x; Ws[(kc + 1) * 68 + row] = wv.y;
    Ws[(kc + 2) * 68 + row] = wv.z; Ws[(kc + 3) * 68 + row] = wv.w;
    wv = *(const float4*)&W[(long)(n0 + row + 32) * 512 + k0 + kc];
    Ws[(kc + 0) * 68 + row + 32] = wv.x; Ws[(kc + 1) * 68 + row + 32] = wv.y;
    Ws[(kc + 2) * 68 + row + 32] = wv.z; Ws[(kc + 3) * 68 + row + 32] = wv.w;
    __syncthreads();
    for (int kk = 0; kk < 32; ++kk) {
      float4 a = *(const float4*)&As[kk * 68 + tm * 4];
      float4 w = *(const float4*)&Ws[kk * 68 + tn * 4];
      acc[0][0] += a.x * w.x; acc[0][1] += a.x * w.y; acc[0][2] += a.x * w.z; acc[0][3] += a.x * w.w;
      acc[1][0] += a.y * w.x; acc[1][1] += a.y * w.y; acc[1][2] += a.y * w.z; acc[1][3] += a.y * w.w;
      acc[2][0] += a.z * w.x; acc[2][1] += a.z * w.y; acc[2][2] += a.z * w.z; acc[2][3] += a.z * w.w;
      acc[3][0] += a.w * w.x; acc[3][1] += a.w * w.y; acc[3][2] += a.w * w.z; acc[3][3] += a.w * w.w;
    }
    __syncthreads();
  }
  float b0v = fb2[n0 + tn * 4 + 0], b1v = fb2[n0 + tn * 4 + 1];
  float b2v = fb2[n0 + tn * 4 + 2], b3v = fb2[n0 + tn * 4 + 3];
#pragma unroll
  for (int mi = 0; mi < 4; ++mi) {
    float4 o;
    o.x = acc[mi][0] + b0v; o.y = acc[mi][1] + b1v;
    o.z = acc[mi][2] + b2v; o.w = acc[mi][3] + b3v;
    *(float4*)&C[(long)(m0 + tm * 4 + mi) * 512 + n0 + tn * 4] = o;
  }
}

extern "C" void kernel_launch(void* const* d_in, const int* in_sizes, int n_in,
                              void* d_out, int out_size, void* d_ws, size_t ws_size,
                              hipStream_t stream) {
  const float* x    = (const float*)d_in[0];
  const float* a12  = (const float*)d_in[1];
  const float* a24  = (const float*)d_in[2];
  const float* a48  = (const float*)d_in[3];
  const float* a96  = (const float*)d_in[4];
  const float* sb   = (const float*)d_in[5];
  const float* g1iw = (const float*)d_in[6];
  const float* g1ib = (const float*)d_in[7];
  const float* g1ow = (const float*)d_in[8];
  const float* g1ob = (const float*)d_in[9];
  const float* g1lg = (const float*)d_in[10];
  const float* g1lb = (const float*)d_in[11];
  const float* g2iw = (const float*)d_in[12];
  const float* g2ib = (const float*)d_in[13];
  const float* g2ow = (const float*)d_in[14];
  const float* g2ob = (const float*)d_in[15];
  const float* g2lg = (const float*)d_in[16];
  const float* g2lb = (const float*)d_in[17];
  const float* fw1  = (const float*)d_in[18];
  const float* fb1  = (const float*)d_in[19];
  const float* fw2  = (const float*)d_in[20];
  const float* fb2  = (const float*)d_in[21];

  if (ws_size < (size_t)WS_FLOATS * sizeof(float)) return;

  float* ws   = (float*)d_ws;
  float* xT   = ws + OFF_XT;
  float* avg  = ws + OFF_AVG;
  int*   per  = (int*)(ws + OFF_PER);
  float* mp   = ws + OFF_MP;
  float* atb  = ws + OFF_AT;
  float* waf  = ws + OFF_WAF;
  float* qat  = ws + OFF_QAT;
  float* vat  = ws + OFF_VAT;
  float* ovt  = ws + OFF_OVT;
  float* cons = ws + OFF_CON;
  float* vbuf = ws + OFF_VB;
  float* mtab = ws + OFF_MT;
  float* def  = ws + OFF_DEF;
  float* zc   = ws + OFF_ZC;
  float* comb = ws + OFF_COMB;
  float* hbuf = ws + OFF_H;
  float* hbu2 = ws + OFF_H2;
  float* out  = (float*)d_out;

  transpose_kernel<<<192, 256, 0, stream>>>(x, xT);
  acf_kernel<<<Cn * 6, 256, 0, stream>>>(xT, avg);
  periods_kernel<<<32, 256, 0, stream>>>(avg, per);
  build_mpinv_kernel<<<190, 256, 0, stream>>>(per, mp);
  prep1<<<224, 256, 0, stream>>>(a12, a24, a48, a96, g1iw, g1ib, g2iw, g2ib, sb,
                                 atb, cons, vbuf);
  wa_gemm2<<<144, 256, 0, stream>>>(g1iw, g2iw, atb, waf, qat, vat);
  prep2<<<336, 256, 0, stream>>>(g1ow, g1ob, g2ow, g2ob, vbuf, cons,
                                 qat, waf, mtab, def, vat, ovt);
  attn_a<<<512, 256, 0, stream>>>(xT, per, mp, mtab, def, zc);
  attn_y<<<256, 256, 0, stream>>>(per, zc, atb, ovt, cons, sb,
                                  g1lg, g1lb, g2lg, g2lb, comb);
  trend_kernel<<<Cn, 256, 0, stream>>>(xT, mp + 1634436L, atb + 84L * 512, sb, comb);
  gemm1_part<<<512, 256, 0, stream>>>(comb, fw1, hbuf, hbu2);
  gemm2_fused<<<256, 256, 0, stream>>>(hbuf, hbu2, fb1, fw2, fb2, out);
}

// Round 12
// 443.978 us; speedup vs baseline: 1.1172x; 1.0314x over previous
//
#include <hip/hip_runtime.h>
#include <math.h>

#define Bn 16
#define Tn 384
#define Cn 128

// ---------------- workspace layout (floats) ----------------
static constexpr long OFF_XT   = 0;
static constexpr long OFF_AVG  = 786432;
static constexpr long OFF_PER  = 835584;
static constexpr long OFF_MP   = 835840;   // low part reused as H3 after attn_a
static constexpr long OFF_AT   = 2507140;
static constexpr long OFF_WAF  = 2605444;
static constexpr long OFF_QAT  = 3195268;
static constexpr long OFF_VAT  = 3391876;
static constexpr long OFF_OVT  = 3588484;
static constexpr long OFF_CON  = 4374916;
static constexpr long OFF_VB   = 4377988;
static constexpr long OFF_MT   = 4379012;
static constexpr long OFF_DEF  = 4673924;
static constexpr long OFF_ZC   = 4677004;  // reused as H2 after attn_y
static constexpr long OFF_COMB = 6643084;
static constexpr long OFF_H    = 9788812;
static constexpr long OFF_H2   = 10837388;
static constexpr long WS_FLOATS = 11885964; // ~47.5 MB

__host__ __device__ inline int nanch(int p) {
  if (p == 384) return 96;
  return (p <= 18) ? 12 : (p <= 36) ? 24 : (p <= 72) ? 48 : 96;
}
__host__ __device__ inline int apre(int n) {
  return (n == 12) ? 0 : (n == 24) ? 12 : (n == 48) ? 36 : 84;
}
__host__ __device__ inline long mpoff(int p) {
  if (p == 384) return 1634436L;
  long T = (long)(p - 1) * p / 2;
  if (p <= 18) return 12 * (T - 6);
  if (p <= 36) return 1980 + 24 * (T - 171);
  if (p <= 72) return 13860 + 48 * (T - 666);
  return 108036 + 96 * (T - 2628);
}

__device__ inline void irow(int j, int newl, int oldl, int& i0, int& i1, float& w) {
  double src = ((double)j + 0.5) * (double)oldl / (double)newl - 0.5;
  if (src < 0.0) src = 0.0;
  double mx = (double)(oldl - 1);
  if (src > mx) src = mx;
  int a = (int)src;
  if (a > oldl - 1) a = oldl - 1;
  i0 = a;
  i1 = (a + 1 < oldl) ? (a + 1) : (oldl - 1);
  w = (float)(src - (double)a);
}

// ---------------- stage 0: transpose x -> xT[c][b][t] ----------------
__global__ __launch_bounds__(256) void transpose_kernel(const float* __restrict__ x,
                                                        float* __restrict__ xT) {
  __shared__ float tile[32 * 129];
  int bid = blockIdx.x;
  int b = bid / 12, t0 = (bid % 12) * 32;
  int tid = threadIdx.x;
  for (int i = tid; i < 32 * 128; i += 256) {
    int tt = i >> 7, cc = i & 127;
    tile[tt * 129 + cc] = x[((long)b * Tn + t0 + tt) * Cn + cc];
  }
  __syncthreads();
  for (int i = tid; i < 32 * 128; i += 256) {
    int cc = i >> 5, tt = i & 31;
    xT[((long)cc * Bn + b) * Tn + t0 + tt] = tile[tt * 129 + cc];
  }
}

// ---------------- stage A1: ACF (writes avg[c][t]) ----------------
__global__ __launch_bounds__(256) void acf_kernel(const float* __restrict__ xT,
                                                  float* __restrict__ avg) {
  __shared__ float xb[Bn * 397];
  __shared__ float mean[Bn];
  int bid = blockIdx.x;
  int c = bid / 6, tile = bid % 6;
  int tid = threadIdx.x;
  for (int i = tid; i < Bn * Tn; i += 256) {
    int b = i / Tn, t = i - b * Tn;
    xb[b * 397 + t] = xT[(long)c * Bn * Tn + i];
  }
  for (int i = tid; i < Bn * 13; i += 256) {
    int b = i / 13, t = Tn + (i - b * 13);
    xb[b * 397 + t] = 0.f;
  }
  __syncthreads();
  if (tid < Bn) {
    float s = 0.f;
    for (int t = 0; t < Tn; ++t) s += xb[tid * 397 + t];
    mean[tid] = s / (float)Tn;
  }
  __syncthreads();
  for (int i = tid; i < Bn * Tn; i += 256) {
    int b = i / Tn, t = i - b * Tn;
    xb[b * 397 + t] -= mean[b];
  }
  __syncthreads();
  int q = tid >> 4;
  int g = tid & 15;
  int tau0 = tile * 64 + q * 4;
  const float* xr = xb + g * 397;
  float a0 = 0.f, a1 = 0.f, a2 = 0.f, a3 = 0.f;
  float w0 = xr[tau0], w1 = xr[tau0 + 1], w2 = xr[tau0 + 2], w3 = xr[tau0 + 3];
  int tmax = Tn - tau0;
  for (int t = 0; t < tmax; ++t) {
    float a = xr[t];
    float wn = xr[t + tau0 + 4];
    a0 += a * w0; a1 += a * w1; a2 += a * w2; a3 += a * w3;
    w0 = w1; w1 = w2; w2 = w3; w3 = wn;
  }
  for (int off = 8; off > 0; off >>= 1) {
    a0 += __shfl_down(a0, off, 16);
    a1 += __shfl_down(a1, off, 16);
    a2 += __shfl_down(a2, off, 16);
    a3 += __shfl_down(a3, off, 16);
  }
  if (g == 0) {
    float* dst = avg + (long)c * Tn + tau0;
    dst[0] = a0; dst[1] = a1; dst[2] = a2; dst[3] = a3;
  }
}

// ---------------- stage A2: peaks ----------------
__global__ __launch_bounds__(256) void periods_kernel(const float* __restrict__ avg,
                                                      int* __restrict__ per) {
  int wv = threadIdx.x >> 6;
  int lane = threadIdx.x & 63;
  int c = blockIdx.x * 4 + wv;
  const float* a = avg + (long)c * Tn;
  const float NEG = -1e30f;
  float b1v = NEG, b2v = NEG;
  int b1i = 0, b2i = 0;
  int t0 = 4 + lane * 6;
#pragma unroll
  for (int i = 0; i < 6; ++i) {
    int t = t0 + i;
    if (t > Tn - 1) break;
    float v = a[t];
    float pv = (t == 4) ? NEG : a[t - 1];
    float nv = (t == Tn - 1) ? NEG : a[t + 1];
    bool peak = (v > pv) && (v > nv) && (v > 0.f);
    float m = peak ? v : NEG;
    if (m > b1v || (m == b1v && t < b1i)) {
      b2v = b1v; b2i = b1i; b1v = m; b1i = t;
    } else if (m > b2v || (m == b2v && t < b2i)) {
      b2v = m; b2i = t;
    }
  }
  for (int off = 32; off > 0; off >>= 1) {
    float c1v = __shfl_down(b1v, off, 64); int c1i = __shfl_down(b1i, off, 64);
    float c2v = __shfl_down(b2v, off, 64); int c2i = __shfl_down(b2i, off, 64);
    if (c1v > b1v || (c1v == b1v && c1i < b1i)) {
      b2v = b1v; b2i = b1i; b1v = c1v; b1i = c1i;
    } else if (c1v > b2v || (c1v == b2v && c1i < b2i)) {
      b2v = c1v; b2i = c1i;
    }
    if (c2v > b1v || (c2v == b1v && c2i < b1i)) {
      b2v = b1v; b2i = b1i; b1v = c2v; b1i = c2i;
    } else if (c2v > b2v || (c2v == b2v && c2i < b2i)) {
      b2v = c2v; b2i = c2i;
    }
  }
  if (lane == 0) {
    per[c * 2 + 0] = min(max(b1i, 4), 192);
    per[c * 2 + 1] = min(max(b2i, 4), 192);
  }
}

// ---------------- stage C: Mpinv via tridiagonal Thomas ----------------
__global__ __launch_bounds__(256) void build_mpinv_kernel(const int* __restrict__ per,
                                                          float* __restrict__ mp) {
  __shared__ int ii[384];
  __shared__ float ww[384];
  __shared__ float dd_[96], ee[96], cp[96], idt[96];
  __shared__ float ginv[96 * 97];
  __shared__ float outp[96 * 97];
  __shared__ int flag;
  int tid = threadIdx.x;
  int p = (blockIdx.x < 189) ? (4 + (int)blockIdx.x) : 384;
  if (tid == 0) flag = (p == 384) ? 1 : 0;
  __syncthreads();
  if (p != 384) {
    for (int i = tid; i < Cn * 2; i += 256)
      if (per[i] == p) flag = 1;
  }
  __syncthreads();
  if (!flag) return;

  int n = nanch(p);
  int m = (p >= n) ? n : p;
  float* dst = mp + mpoff(p);

  for (int j = tid; j < p; j += 256) {
    int i0, i1; float w;
    irow(j, p, n, i0, i1, w);
    ii[j] = i0; ww[j] = w;
  }
  for (int i = tid; i < m; i += 256) { dd_[i] = 0.f; ee[i] = 0.f; }
  __syncthreads();

  if (p >= n) {
    for (int j = tid; j < p; j += 256) {
      int i0 = ii[j]; float w = ww[j];
      int i1 = min(i0 + 1, n - 1);
      if (i1 == i0) {
        atomicAdd(&dd_[i0], 1.0f);
      } else {
        float a = 1.f - w, b = w;
        atomicAdd(&dd_[i0], a * a);
        atomicAdd(&dd_[i1], b * b);
        atomicAdd(&ee[i0], a * b);
      }
    }
  } else {
    for (int r = tid; r < p; r += 256) {
      int i0 = ii[r]; float w = ww[r];
      int i1 = min(i0 + 1, n - 1);
      float a, b; int c0 = i0, c1 = i1;
      if (i1 == i0) { a = 1.f; b = 0.f; c1 = -1; }
      else { a = 1.f - w; b = w; }
      dd_[r] = a * a + b * b;
      if (r < p - 1) {
        int j0 = ii[r + 1]; float w2 = ww[r + 1];
        int j1 = min(j0 + 1, n - 1);
        float a2, b2; int d0 = j0, d1 = j1;
        if (j1 == j0) { a2 = 1.f; b2 = 0.f; d1 = -2; }
        else { a2 = 1.f - w2; b2 = w2; }
        float s = 0.f;
        if (c0 == d0) s += a * a2;
        if (c0 == d1) s += a * b2;
        if (c1 == d0) s += b * a2;
        if (c1 == d1) s += b * b2;
        ee[r] = s;
      }
    }
  }
  __syncthreads();
  if (tid == 0) {
    float dt = dd_[0];
    idt[0] = 1.f / dt;
    for (int i = 1; i < m; ++i) {
      float c = ee[i - 1] * idt[i - 1];
      cp[i - 1] = c;
      dt = dd_[i] - ee[i - 1] * c;
      idt[i] = 1.f / dt;
    }
  }
  __syncthreads();
  if (tid < m) {
    int j = tid;
    float z = 1.f;
    ginv[j * 97 + j] = 1.f;
    for (int i = j + 1; i < m; ++i) {
      z = -cp[i - 1] * z;
      ginv[i * 97 + j] = z;
    }
    float xn = ginv[(m - 1) * 97 + j] * idt[m - 1];
    ginv[(m - 1) * 97 + j] = xn;
    for (int i = m - 2; i >= 0; --i) {
      float zi = (i >= j) ? ginv[i * 97 + j] : 0.f;
      xn = zi * idt[i] - cp[i] * xn;
      ginv[i * 97 + j] = xn;
    }
  }
  __syncthreads();
  if (p >= n) {
    for (int idx = tid; idx < p * n; idx += 256) {
      int t = idx / n, k = idx - t * n;
      int i0 = ii[t]; float w = ww[t];
      int i1 = min(i0 + 1, n - 1);
      dst[idx] = (1.f - w) * ginv[i0 * 97 + k] + w * ginv[i1 * 97 + k];
    }
  } else {
    for (int t = tid; t < p; t += 256) {
      for (int k = 0; k < n; ++k) outp[t * 97 + k] = 0.f;
      for (int j = 0; j < p; ++j) {
        float hv = ginv[t * 97 + j];
        int i0 = ii[j]; float w = ww[j];
        int i1 = min(i0 + 1, n - 1);
        outp[t * 97 + i0] += hv * (1.f - w);
        outp[t * 97 + i1] += hv * w;
      }
    }
    __syncthreads();
    for (int idx = tid; idx < p * n; idx += 256) {
      int t = idx / n, k = idx - t * n;
      dst[idx] = outp[t * 97 + k];
    }
  }
}

// ---------------- prep1: anchors^T + constsA merged ----------------
__device__ void at_body(int bid, const float* __restrict__ a12,
                        const float* __restrict__ a24, const float* __restrict__ a48,
                        const float* __restrict__ a96, float* __restrict__ at_tab,
                        float* tile) {
  int a = bid >> 3, d0 = (bid & 7) * 64;
  int n = (a == 0) ? 12 : (a == 1) ? 24 : (a == 2) ? 48 : 96;
  const float* src = (a == 0) ? a12 : (a == 1) ? a24 : (a == 2) ? a48 : a96;
  float* dst = at_tab + (long)apre(n) * 512;
  int tid = threadIdx.x;
  for (int i = tid; i < 64 * n; i += 256) {
    int dd = i / n, k = i - dd * n;
    tile[dd * 97 + k] = src[(long)(d0 + dd) * n + (long)k];
  }
  __syncthreads();
  for (int i = tid; i < n * 64; i += 256) {
    int k = i >> 6, dd = i & 63;
    dst[(long)k * 512 + d0 + dd] = tile[dd * 97 + k];
  }
  if (bid == 0) {
    for (int i = tid; i < 12 * 512; i += 256) at_tab[180L * 512 + i] = 0.f;
  }
}

__device__ void constsA_body(int bid, const float* __restrict__ i1w,
                             const float* __restrict__ i1b, const float* __restrict__ i2w,
                             const float* __restrict__ i2b, const float* __restrict__ sb,
                             float* __restrict__ cons, float* __restrict__ vbuf,
                             float* sv) {
  int s = bid / 96, r0 = (bid % 96) * 16;
  const float* inw = s ? i2w : i1w;
  const float* inb = s ? i2b : i1b;
  int tid = threadIdx.x;
  for (int i = tid; i < 512; i += 256) sv[i] = sb[i];
  __syncthreads();
  int lane = tid & 63, w = tid >> 6;
  for (int rr = 0; rr < 4; ++rr) {
    int r = r0 + w * 4 + rr;
    const float* row = inw + (long)r * 512;
    float part = 0.f;
    for (int kk = 0; kk < 8; ++kk) part += row[lane + 64 * kk] * sv[lane + 64 * kk];
    for (int off = 32; off > 0; off >>= 1) part += __shfl_down(part, off, 64);
    if (lane == 0) {
      float v = part + inb[r];
      if (r < 1024) cons[s * 1536 + r] = v;
      else vbuf[s * 512 + (r - 1024)] = v;
    }
  }
}

__global__ __launch_bounds__(256) void prep1(const float* __restrict__ a12,
                                             const float* __restrict__ a24,
                                             const float* __restrict__ a48,
                                             const float* __restrict__ a96,
                                             const float* __restrict__ i1w,
                                             const float* __restrict__ i1b,
                                             const float* __restrict__ i2w,
                                             const float* __restrict__ i2b,
                                             const float* __restrict__ sb,
                                             float* __restrict__ at_tab,
                                             float* __restrict__ cons,
                                             float* __restrict__ vbuf) {
  __shared__ float sm[64 * 97];
  int bid = blockIdx.x;
  if (bid < 32) at_body(bid, a12, a24, a48, a96, at_tab, sm);
  else constsA_body(bid - 32, i1w, i1b, i2w, i2b, sb, cons, vbuf, sm);
}

// ---------------- stage P2: WAfull = in_w @ A_cat ----------------
__global__ __launch_bounds__(256) void wa_gemm2(const float* __restrict__ iw0,
                                                const float* __restrict__ iw1,
                                                const float* __restrict__ atb,
                                                float* __restrict__ waf,
                                                float* __restrict__ qat,
                                                float* __restrict__ vat) {
  __shared__ float smem[2 * 32 * 68];
  float* As = smem;
  float* Ws = smem + 32 * 68;
  int bid = blockIdx.x;
  int s = bid / 72, r = bid % 72;
  int m0 = (r / 3) * 64, n0 = (r % 3) * 64;
  const float* A = s ? iw1 : iw0;
  float* wafs = waf + (long)s * 294912;
  int tid = threadIdx.x;
  int tm = tid & 15, tn = tid >> 4;
  float acc[4][4];
#pragma unroll
  for (int i = 0; i < 4; ++i)
#pragma unroll
    for (int j = 0; j < 4; ++j) acc[i][j] = 0.f;
  int row = tid >> 3, kc = (tid & 7) * 4;
  for (int k0 = 0; k0 < 512; k0 += 32) {
    float4 v = *(const float4*)&A[(long)(m0 + row) * 512 + k0 + kc];
    As[(kc + 0) * 68 + row] = v.x; As[(kc + 1) * 68 + row] = v.y;
    As[(kc + 2) * 68 + row] = v.z; As[(kc + 3) * 68 + row] = v.w;
    v = *(const float4*)&A[(long)(m0 + row + 32) * 512 + k0 + kc];
    As[(kc + 0) * 68 + row + 32] = v.x; As[(kc + 1) * 68 + row + 32] = v.y;
    As[(kc + 2) * 68 + row + 32] = v.z; As[(kc + 3) * 68 + row + 32] = v.w;
    v = *(const float4*)&atb[(long)(n0 + row) * 512 + k0 + kc];
    Ws[(kc + 0) * 68 + row] = v.x; Ws[(kc + 1) * 68 + row] = v.y;
    Ws[(kc + 2) * 68 + row] = v.z; Ws[(kc + 3) * 68 + row] = v.w;
    v = *(const float4*)&atb[(long)(n0 + row + 32) * 512 + k0 + kc];
    Ws[(kc + 0) * 68 + row + 32] = v.x; Ws[(kc + 1) * 68 + row + 32] = v.y;
    Ws[(kc + 2) * 68 + row + 32] = v.z; Ws[(kc + 3) * 68 + row + 32] = v.w;
    __syncthreads();
    for (int kk = 0; kk < 32; ++kk) {
      float4 a = *(const float4*)&As[kk * 68 + tm * 4];
      float4 w = *(const float4*)&Ws[kk * 68 + tn * 4];
      acc[0][0] += a.x * w.x; acc[0][1] += a.x * w.y; acc[0][2] += a.x * w.z; acc[0][3] += a.x * w.w;
      acc[1][0] += a.y * w.x; acc[1][1] += a.y * w.y; acc[1][2] += a.y * w.z; acc[1][3] += a.y * w.w;
      acc[2][0] += a.z * w.x; acc[2][1] += a.z * w.y; acc[2][2] += a.z * w.z; acc[2][3] += a.z * w.w;
      acc[3][0] += a.w * w.x; acc[3][1] += a.w * w.y; acc[3][2] += a.w * w.z; acc[3][3] += a.w * w.w;
    }
    __syncthreads();
  }
#pragma unroll
  for (int mi = 0; mi < 4; ++mi) {
    float4 o;
    o.x = acc[mi][0]; o.y = acc[mi][1]; o.z = acc[mi][2]; o.w = acc[mi][3];
    *(float4*)&wafs[(long)(m0 + tm * 4 + mi) * 192 + n0 + tn * 4] = o;
  }
  if (m0 < 512 || m0 >= 1024) {
    float* Ct = smem;
#pragma unroll
    for (int mi = 0; mi < 4; ++mi)
#pragma unroll
      for (int j = 0; j < 4; ++j)
        Ct[(tn * 4 + j) * 65 + tm * 4 + mi] = acc[mi][j];
    __syncthreads();
    float* dst = ((m0 < 512) ? qat : vat) + (long)s * 98304;
    int mr = m0 & 511;
    for (int i = tid; i < 64 * 64; i += 256) {
      int cc = i >> 6, rr = i & 63;
      dst[(long)(n0 + cc) * 512 + mr + rr] = Ct[cc * 65 + rr];
    }
  }
}

// ---------------- prep2 bodies ----------------
__device__ void constsB_body(int bid, const float* __restrict__ o1w,
                             const float* __restrict__ o1b, const float* __restrict__ o2w,
                             const float* __restrict__ o2b, const float* __restrict__ vbuf,
                             float* __restrict__ cons, float* vv) {
  int s = bid / 32, r0 = (bid % 32) * 16;
  const float* outw = s ? o2w : o1w;
  const float* outb = s ? o2b : o1b;
  int tid = threadIdx.x;
  for (int i = tid; i < 512; i += 256) vv[i] = vbuf[s * 512 + i];
  __syncthreads();
  int lane = tid & 63, w = tid >> 6;
  for (int rr = 0; rr < 4; ++rr) {
    int r = r0 + w * 4 + rr;
    const float* row = outw + (long)r * 512;
    float part = 0.f;
    for (int kk = 0; kk < 8; ++kk) part += row[lane + 64 * kk] * vv[lane + 64 * kk];
    for (int off = 32; off > 0; off >>= 1) part += __shfl_down(part, off, 64);
    if (lane == 0) cons[s * 1536 + 1024 + r] = part + outb[r];
  }
}

__device__ void mt_body(int bid, const float* __restrict__ qat,
                        const float* __restrict__ waf, float* __restrict__ mt,
                        float* As, float* Ws) {
  int s4h = bid / 9, t = bid % 9;
  int s = s4h >> 2, h = s4h & 3;
  int m0 = (t / 3) * 64, n0 = (t % 3) * 64;
  const float* A = qat + (long)s * 98304 + h * 128;
  const float* B = waf + (long)s * 294912 + 98304 + (long)(h * 128) * 192;
  float* C = mt + (long)s4h * 36864;
  int tid = threadIdx.x;
  int tm = tid & 15, tn = tid >> 4;
  float acc[4][4];
#pragma unroll
  for (int i = 0; i < 4; ++i)
#pragma unroll
    for (int j = 0; j < 4; ++j) acc[i][j] = 0.f;
  int row = tid >> 3, kc = (tid & 7) * 4;
  for (int k0 = 0; k0 < 128; k0 += 32) {
    float4 v = *(const float4*)&A[(long)(m0 + row) * 512 + k0 + kc];
    As[(kc + 0) * 68 + row] = v.x; As[(kc + 1) * 68 + row] = v.y;
    As[(kc + 2) * 68 + row] = v.z; As[(kc + 3) * 68 + row] = v.w;
    v = *(const float4*)&A[(long)(m0 + row + 32) * 512 + k0 + kc];
    As[(kc + 0) * 68 + row + 32] = v.x; As[(kc + 1) * 68 + row + 32] = v.y;
    As[(kc + 2) * 68 + row + 32] = v.z; As[(kc + 3) * 68 + row + 32] = v.w;
    for (int l = tid; l < 512; l += 256) {
      int i = l >> 4, kq = (l & 15) * 4;
      float4 b = *(const float4*)&B[(long)(k0 + i) * 192 + n0 + kq];
      Ws[i * 68 + kq + 0] = b.x; Ws[i * 68 + kq + 1] = b.y;
      Ws[i * 68 + kq + 2] = b.z; Ws[i * 68 + kq + 3] = b.w;
    }
    __syncthreads();
    for (int kk = 0; kk < 32; ++kk) {
      float4 a = *(const float4*)&As[kk * 68 + tm * 4];
      float4 w = *(const float4*)&Ws[kk * 68 + tn * 4];
      acc[0][0] += a.x * w.x; acc[0][1] += a.x * w.y; acc[0][2] += a.x * w.z; acc[0][3] += a.x * w.w;
      acc[1][0] += a.y * w.x; acc[1][1] += a.y * w.y; acc[1][2] += a.y * w.z; acc[1][3] += a.y * w.w;
      acc[2][0] += a.z * w.x; acc[2][1] += a.z * w.y; acc[2][2] += a.z * w.z; acc[2][3] += a.z * w.w;
      acc[3][0] += a.w * w.x; acc[3][1] += a.w * w.y; acc[3][2] += a.w * w.z; acc[3][3] += a.w * w.w;
    }
    __syncthreads();
  }
#pragma unroll
  for (int mi = 0; mi < 4; ++mi) {
    float4 o;
    o.x = acc[mi][0]; o.y = acc[mi][1]; o.z = acc[mi][2]; o.w = acc[mi][3];
    *(float4*)&C[(long)(m0 + tm * 4 + mi) * 192 + n0 + tn * 4] = o;
  }
}

__device__ void sc_body(int bid, const float* __restrict__ qat,
                        const float* __restrict__ waf, const float* __restrict__ cons,
                        float* __restrict__ def, float* qcl, float* kbl) {
  int s = bid >> 2, h = bid & 3;
  int tid = threadIdx.x;
  const float* qc = cons + s * 1536;
  const float* kb = qc + 512;
  if (tid < 128) {
    qcl[tid] = qc[h * 128 + tid];
    kbl[tid] = kb[h * 128 + tid];
  }
  __syncthreads();
  const float* katb = waf + (long)s * 294912 + 98304;
  const float* qats = qat + (long)s * 98304;
  float* dtab = def + (long)(s * 4 + h) * 192;
  float* etab = def + 1536 + (long)(s * 4 + h) * 192;
  float* ftab = def + 3072 + (s * 4 + h);
  if (tid < 192) {
    float acc = 0.f;
    for (int i = 0; i < 128; ++i) acc += katb[(long)(h * 128 + i) * 192 + tid] * qcl[i];
    dtab[tid] = acc;
    float acc2 = 0.f;
    const float* qr = qats + (long)tid * 512 + h * 128;
    for (int i = 0; i < 128; ++i) acc2 += qr[i] * kbl[i];
    etab[tid] = acc2;
  }
  if (tid < 64) {
    float acc = 0.f;
    for (int i = tid; i < 128; i += 64) acc += qcl[i] * kbl[i];
    for (int off = 32; off > 0; off >>= 1) acc += __shfl_down(acc, off, 64);
    if (tid == 0) *ftab = acc;
  }
}

__device__ void ova_body(int bid, const float* __restrict__ ow0,
                         const float* __restrict__ ow1, const float* __restrict__ vat,
                         float* __restrict__ ovt, float* As, float* Ws) {
  int s = bid / 96, r = bid % 96;
  int h = r / 24, r2 = r % 24;
  int m0 = (r2 / 8) * 64, n0 = (r2 % 8) * 64;
  const float* A = vat + (long)s * 98304 + h * 128;
  const float* W = (s ? ow1 : ow0) + h * 128;
  float* C = ovt + ((long)(s * 4 + h) * 192) * 512;
  int tid = threadIdx.x;
  int tm = tid & 15, tn = tid >> 4;
  float acc[4][4];
#pragma unroll
  for (int i = 0; i < 4; ++i)
#pragma unroll
    for (int j = 0; j < 4; ++j) acc[i][j] = 0.f;
  int row = tid >> 3, kc = (tid & 7) * 4;
  for (int k0 = 0; k0 < 128; k0 += 32) {
    float4 v = *(const float4*)&A[(long)(m0 + row) * 512 + k0 + kc];
    As[(kc + 0) * 68 + row] = v.x; As[(kc + 1) * 68 + row] = v.y;
    As[(kc + 2) * 68 + row] = v.z; As[(kc + 3) * 68 + row] = v.w;
    v = *(const float4*)&A[(long)(m0 + row + 32) * 512 + k0 + kc];
    As[(kc + 0) * 68 + row + 32] = v.x; As[(kc + 1) * 68 + row + 32] = v.y;
    As[(kc + 2) * 68 + row + 32] = v.z; As[(kc + 3) * 68 + row + 32] = v.w;
    v = *(const float4*)&W[(long)(n0 + row) * 512 + k0 + kc];
    Ws[(kc + 0) * 68 + row] = v.x; Ws[(kc + 1) * 68 + row] = v.y;
    Ws[(kc + 2) * 68 + row] = v.z; Ws[(kc + 3) * 68 + row] = v.w;
    v = *(const float4*)&W[(long)(n0 + row + 32) * 512 + k0 + kc];
    Ws[(kc + 0) * 68 + row + 32] = v.x; Ws[(kc + 1) * 68 + row + 32] = v.y;
    Ws[(kc + 2) * 68 + row + 32] = v.z; Ws[(kc + 3) * 68 + row + 32] = v.w;
    __syncthreads();
    for (int kk = 0; kk < 32; ++kk) {
      float4 a = *(const float4*)&As[kk * 68 + tm * 4];
      float4 w = *(const float4*)&Ws[kk * 68 + tn * 4];
      acc[0][0] += a.x * w.x; acc[0][1] += a.x * w.y; acc[0][2] += a.x * w.z; acc[0][3] += a.x * w.w;
      acc[1][0] += a.y * w.x; acc[1][1] += a.y * w.y; acc[1][2] += a.y * w.z; acc[1][3] += a.y * w.w;
      acc[2][0] += a.z * w.x; acc[2][1] += a.z * w.y; acc[2][2] += a.z * w.z; acc[2][3] += a.z * w.w;
      acc[3][0] += a.w * w.x; acc[3][1] += a.w * w.y; acc[3][2] += a.w * w.z; acc[3][3] += a.w * w.w;
    }
    __syncthreads();
  }
#pragma unroll
  for (int mi = 0; mi < 4; ++mi) {
    float4 o;
    o.x = acc[mi][0]; o.y = acc[mi][1]; o.z = acc[mi][2]; o.w = acc[mi][3];
    *(float4*)&C[(long)(m0 + tm * 4 + mi) * 512 + n0 + tn * 4] = o;
  }
}

__global__ __launch_bounds__(256) void prep2(const float* __restrict__ o1w,
                                             const float* __restrict__ o1b,
                                             const float* __restrict__ o2w,
                                             const float* __restrict__ o2b,
                                             const float* __restrict__ vbuf,
                                             float* __restrict__ cons,
                                             const float* __restrict__ qat,
                                             const float* __restrict__ waf,
                                             float* __restrict__ mtab,
                                             float* __restrict__ def,
                                             const float* __restrict__ vat,
                                             float* __restrict__ ovt) {
  __shared__ float sm[2 * 32 * 68];
  int bid = blockIdx.x;
  if (bid < 64) constsB_body(bid, o1w, o1b, o2w, o2b, vbuf, cons, sm);
  else if (bid < 136) mt_body(bid - 64, qat, waf, mtab, sm, sm + 32 * 68);
  else if (bid < 144) sc_body(bid - 136, qat, waf, cons, def, sm, sm + 128);
  else ova_body(bid - 144, o1w, o2w, vat, ovt, sm, sm + 32 * 68);
}

// ---------------- stage B1: attn_a — Z, scores, softmax, zh -> zcat ----------------
__global__ __launch_bounds__(256) void attn_a(
    const float* __restrict__ xT, const int* __restrict__ per,
    const float* __restrict__ mp, const float* __restrict__ mt,
    const float* __restrict__ def, float* __restrict__ zc) {
  __shared__ float xb[8 * 384];
  __shared__ float Z[8 * 1248];
  __shared__ float zl[8 * 96];
  __shared__ float arb[8 * 384];
  __shared__ float qkc[32];
  float* scp = xb;

  int tid = threadIdx.x;
  int bid = blockIdx.x;
  int slot = bid & 1;
  int c = (bid >> 1) & 127;
  int b0 = (bid >> 8) * 8;
  int p = per[c * 2 + slot];
  int n = nanch(p);
  int np = Tn / p;
  int n1 = n + 1;
  float s = sqrtf((float)p / (float)n);
  float s2 = s * s;
  const float rscale = 0.08838834764831845f;
  int pre = apre(n);
  const float* mpp = mp + mpoff(p);
  const float* dt = def + (long)(slot * 4) * 192;
  const float* et = def + 1536 + (long)(slot * 4) * 192;
  const float* ft = def + 3072 + slot * 4;
  const float* mtb = mt + (long)(slot * 4) * 36864;

  for (int g = 0; g < 8; ++g)
    for (int t = tid; t < Tn; t += 256)
      xb[g * 384 + t] = xT[((long)c * Bn + b0 + g) * Tn + t];
  __syncthreads();

  // Ph1: Z = patches @ Mpinv (8-way g-fused, k-pairs, float2 Mpinv loads)
  {
    int half = n >> 1;
    int tot1 = np * half;
    for (int idx = tid; idx < tot1; idx += 256) {
      int j = idx / half, k2 = idx - j * half;
      int k = k2 * 2;
      int jb = j * p;
      const float* mk = mpp + k;
      float a0[8], a1[8];
#pragma unroll
      for (int g = 0; g < 8; ++g) { a0[g] = 0.f; a1[g] = 0.f; }
      for (int t = 0; t < p; ++t) {
        float2 m = *(const float2*)&mk[(long)t * n];
#pragma unroll
        for (int g = 0; g < 8; ++g) {
          float xv = xb[g * 384 + jb + t];
          a0[g] += m.x * xv;
          a1[g] += m.y * xv;
        }
      }
      int zi = j * n1 + k;
#pragma unroll
      for (int g = 0; g < 8; ++g) {
        Z[g * 1248 + zi] = a0[g];
        Z[g * 1248 + zi + 1] = a1[g];
      }
    }
  }
  __syncthreads();

  for (int idx = tid; idx < 8 * n; idx += 256) {
    int g = idx / n, k = idx - g * n;
    zl[g * 96 + k] = Z[g * 1248 + (np - 1) * n1 + k];
  }
  __syncthreads();

  {
    int pair = tid >> 3, l = tid & 7;
    int g = pair >> 2, h = pair & 3;
    const float* eh = et + h * 192 + pre;
    float acc = 0.f;
    for (int j = l; j < n; j += 8) acc += eh[j] * zl[g * 96 + j];
    for (int off = 4; off > 0; off >>= 1) acc += __shfl_down(acc, off, 8);
    if (l == 0) qkc[g * 4 + h] = s * acc + ft[h];
  }
  {
    int tot = 4 * n;
    for (int idx = tid; idx < tot; idx += 256) {
      int h = idx / n, k = idx - h * n;
      const float* mtc = mtb + (long)h * 36864 + (long)pre * 192 + pre + k;
      float a[8];
#pragma unroll
      for (int g = 0; g < 8; ++g) a[g] = 0.f;
      for (int j0 = 0; j0 < n; j0 += 4) {
        float4 zb[8];
#pragma unroll
        for (int g = 0; g < 8; ++g) zb[g] = *(const float4*)&zl[g * 96 + j0];
#pragma unroll
        for (int c4 = 0; c4 < 4; ++c4) {
          float mv = mtc[(long)(j0 + c4) * 192];
#pragma unroll
          for (int g = 0; g < 8; ++g) {
            float zv = (c4 == 0) ? zb[g].x : (c4 == 1) ? zb[g].y : (c4 == 2) ? zb[g].z : zb[g].w;
            a[g] += mv * zv;
          }
        }
      }
      float dv = dt[h * 192 + pre + k];
#pragma unroll
      for (int g = 0; g < 8; ++g) arb[g * 384 + h * 96 + k] = s2 * a[g] + s * dv;
    }
  }
  __syncthreads();

  // scores
  {
    int fnp = 4 * np;
    int tot = 8 * fnp;
    for (int idx = tid; idx < tot; idx += 256) {
      int g = idx / fnp;
      int r = idx - g * fnp;
      int h = r / np, j = r - h * np;
      const float* ap = arb + g * 384 + h * 96;
      const float* zp = Z + g * 1248 + j * n1;
      float acc = 0.f;
      for (int k = 0; k < n; ++k) acc += ap[k] * zp[k];
      scp[g * 384 + h * np + j] = (acc + qkc[g * 4 + h]) * rscale;
    }
  }
  __syncthreads();

  // softmax
  {
    int pair = tid >> 3, l = tid & 7;
    int g = pair >> 2, h = pair & 3;
    float* sp = scp + g * 384 + h * np;
    float m = -1e30f;
    for (int j = l; j < np; j += 8) m = fmaxf(m, sp[j]);
    for (int off = 4; off > 0; off >>= 1) m = fmaxf(m, __shfl_xor(m, off, 8));
    float lsum = 0.f;
    for (int j = l; j < np; j += 8) { float e = expf(sp[j] - m); sp[j] = e; lsum += e; }
    for (int off = 4; off > 0; off >>= 1) lsum += __shfl_xor(lsum, off, 8);
    float il = 1.f / lsum;
    for (int j = l; j < np; j += 8) sp[j] *= il;
  }
  __syncthreads();

  // zh
  {
    int fn = 4 * n;
    int tot = 8 * fn;
    for (int idx = tid; idx < tot; idx += 256) {
      int g = idx / fn;
      int r = idx - g * fn;
      int h = r / n, k = r - h * n;
      const float* sp = scp + g * 384 + h * np;
      const float* zp = Z + g * 1248 + k;
      float acc = 0.f;
      for (int j = 0; j < np; ++j) acc += sp[j] * zp[j * n1];
      arb[g * 384 + h * 96 + k] = acc;
    }
  }
  __syncthreads();

  // write zcat (s-scaled)
  {
    long rowb = ((long)slot * 128 + c) * 16 + b0;
    int fn5 = 5 * n;
    int tot = 8 * fn5;
    for (int idx = tid; idx < tot; idx += 256) {
      int g = idx / fn5, r = idx - g * fn5;
      int seg = r / n, k = r - seg * n;
      float v = (seg == 0) ? zl[g * 96 + k] : arb[g * 384 + (seg - 1) * 96 + k];
      zc[(rowb + g) * 480 + seg * 96 + k] = s * v;
    }
  }
}

// ---------------- stage B2: attn_y ----------------
__global__ __launch_bounds__(256) void attn_y(
    const int* __restrict__ per, const float* __restrict__ zc,
    const float* __restrict__ at_tab, const float* __restrict__ ovt,
    const float* __restrict__ cons, const float* __restrict__ sb,
    const float* __restrict__ l1g, const float* __restrict__ l1b,
    const float* __restrict__ l2g, const float* __restrict__ l2b,
    float* __restrict__ comb) {
  __shared__ float zbuf[16 * 480];
  __shared__ float red[128];
  __shared__ float stats[32];
  int tid = threadIdx.x;
  int bid = blockIdx.x;
  int slot = bid & 1, c = bid >> 1;
  int p = per[c * 2 + slot];
  int n = nanch(p);
  int pre = apre(n);
  const float* atb = at_tab + (long)pre * 512;
  const float* oc = cons + slot * 1536 + 1024;
  const float* lng = slot ? l2g : l1g;
  const float* lnb = slot ? l2b : l1b;
  long rowb = ((long)slot * 128 + c) * 16;
  int fn5 = 5 * n;
  for (int idx = tid; idx < 16 * fn5; idx += 256) {
    int g = idx / fn5, r = idx - g * fn5;
    int seg = r / n, k = r - seg * n;
    zbuf[g * 480 + seg * 96 + k] = zc[(rowb + g) * 480 + seg * 96 + k];
  }
  __syncthreads();
  int d0 = 2 * tid;
  float acc0[16], acc1[16];
#pragma unroll
  for (int r = 0; r < 16; ++r) { acc0[r] = 0.f; acc1[r] = 0.f; }
  for (int seg = 0; seg < 5; ++seg) {
    const float* wt = (seg == 0) ? atb
                                 : (ovt + ((long)(slot * 4 + seg - 1) * 192 + pre) * 512);
    int zoff = seg * 96;
    for (int k0 = 0; k0 < n; k0 += 4) {
      float4 zv[16];
#pragma unroll
      for (int r = 0; r < 16; ++r) zv[r] = *(const float4*)&zbuf[r * 480 + zoff + k0];
#pragma unroll
      for (int c4 = 0; c4 < 4; ++c4) {
        float2 w = *(const float2*)&wt[(long)(k0 + c4) * 512 + d0];
#pragma unroll
        for (int r = 0; r < 16; ++r) {
          float z = (c4 == 0) ? zv[r].x : (c4 == 1) ? zv[r].y : (c4 == 2) ? zv[r].z : zv[r].w;
          acc0[r] += w.x * z;
          acc1[r] += w.y * z;
        }
      }
    }
  }
  float2 sbv = *(const float2*)&sb[d0];
  float2 ocv = *(const float2*)&oc[d0];
  float s0 = sbv.x + ocv.x, s1 = sbv.y + ocv.y;
#pragma unroll
  for (int r = 0; r < 16; ++r) { acc0[r] += s0; acc1[r] += s1; }
  float ps[32];
#pragma unroll
  for (int r = 0; r < 16; ++r) {
    ps[2 * r] = acc0[r] + acc1[r];
    ps[2 * r + 1] = acc0[r] * acc0[r] + acc1[r] * acc1[r];
  }
  int w = tid >> 6, lane = tid & 63;
  for (int off = 32; off > 0; off >>= 1) {
#pragma unroll
    for (int i = 0; i < 32; ++i) ps[i] += __shfl_down(ps[i], off, 64);
  }
  if (lane == 0) {
#pragma unroll
    for (int i = 0; i < 32; ++i) red[w * 32 + i] = ps[i];
  }
  __syncthreads();
  if (tid < 16) {
    int r = tid;
    float ssum = red[2 * r] + red[32 + 2 * r] + red[64 + 2 * r] + red[96 + 2 * r];
    float qsum = red[2 * r + 1] + red[32 + 2 * r + 1] + red[64 + 2 * r + 1] + red[96 + 2 * r + 1];
    float mu = ssum / 512.f;
    float var = qsum / 512.f - mu * mu;
    stats[2 * r] = mu;
    stats[2 * r + 1] = rsqrtf(var + 1e-5f);
  }
  __syncthreads();
  float2 gv = *(const float2*)&lng[d0];
  float2 bv = *(const float2*)&lnb[d0];
#pragma unroll
  for (int r = 0; r < 16; ++r) {
    float mu = stats[2 * r], rstd = stats[2 * r + 1];
    long base = ((long)r * Cn + c) * 1536 + slot * 512;
    float2 o;
    o.x = (acc0[r] - mu) * rstd * gv.x + bv.x;
    o.y = (acc1[r] - mu) * rstd * gv.y + bv.y;
    *(float2*)&comb[base + d0] = o;
  }
}

// ---------------- stage D: trend ----------------
__global__ __launch_bounds__(256) void trend_kernel(const float* __restrict__ xT,
                                                    const float* __restrict__ mp384,
                                                    const float* __restrict__ at96,
                                                    const float* __restrict__ sb,
                                                    float* __restrict__ comb) {
  __shared__ float xb[Bn * Tn];
  __shared__ float Ztr[Bn * 97];
  int c = blockIdx.x, tid = threadIdx.x;
  for (int i = tid; i < Bn * Tn; i += 256) xb[i] = xT[(long)c * Bn * Tn + i];
  __syncthreads();
  for (int idx = tid; idx < 4 * 96; idx += 256) {
    int bq = idx / 96, k = idx - bq * 96;
    const float* x0 = xb + (bq * 4 + 0) * Tn;
    const float* x1 = xb + (bq * 4 + 1) * Tn;
    const float* x2 = xb + (bq * 4 + 2) * Tn;
    const float* x3 = xb + (bq * 4 + 3) * Tn;
    const float* mk = mp384 + k;
    float a0 = 0.f, a1 = 0.f, a2 = 0.f, a3 = 0.f;
    for (int t = 0; t < Tn; ++t) {
      float m = mk[(long)t * 96];
      a0 += m * x0[t]; a1 += m * x1[t]; a2 += m * x2[t]; a3 += m * x3[t];
    }
    Ztr[(bq * 4 + 0) * 97 + k] = a0;
    Ztr[(bq * 4 + 1) * 97 + k] = a1;
    Ztr[(bq * 4 + 2) * 97 + k] = a2;
    Ztr[(bq * 4 + 3) * 97 + k] = a3;
  }
  __syncthreads();
  float acc0[Bn], acc1[Bn];
#pragma unroll
  for (int b = 0; b < Bn; ++b) { acc0[b] = 0.f; acc1[b] = 0.f; }
  for (int k = 0; k < 96; ++k) {
    float w0 = at96[(long)k * 512 + tid];
    float w1 = at96[(long)k * 512 + 256 + tid];
#pragma unroll
    for (int b = 0; b < Bn; ++b) {
      float z = Ztr[b * 97 + k];
      acc0[b] += w0 * z;
      acc1[b] += w1 * z;
    }
  }
  float s0 = sb[tid], s1 = sb[256 + tid];
#pragma unroll
  for (int b = 0; b < Bn; ++b) {
    long base = ((long)b * Cn + c) * 1536 + 1024;
    comb[base + tid] = 2.f * acc0[b] + s0;
    comb[base + 256 + tid] = 2.f * acc1[b] + s1;
  }
}

// ---------------- stage E1: fusion GEMM-1, split-K x4, simple single-buffer ----------------
__global__ __launch_bounds__(256) void gemm1_part(const float* __restrict__ A,
                                                  const float* __restrict__ W,
                                                  float* __restrict__ C0,
                                                  float* __restrict__ C1,
                                                  float* __restrict__ C2,
                                                  float* __restrict__ C3) {
  __shared__ float As[32 * 68];
  __shared__ float Ws[32 * 68];
  int bid = blockIdx.x;
  int kh = bid >> 8;                 // 0..3
  int r = bid & 255;
  int m0 = (r >> 3) * 64, n0 = (r & 7) * 64;
  float* C = (kh == 0) ? C0 : (kh == 1) ? C1 : (kh == 2) ? C2 : C3;
  const float* Ab = A + kh * 384;
  const float* Wb = W + kh * 384;
  int tid = threadIdx.x;
  int tm = tid & 15, tn = tid >> 4;
  float acc[4][4];
#pragma unroll
  for (int i = 0; i < 4; ++i)
#pragma unroll
    for (int j = 0; j < 4; ++j) acc[i][j] = 0.f;
  int row = tid >> 3, kc = (tid & 7) * 4;
  for (int k0 = 0; k0 < 384; k0 += 32) {
    float4 v = *(const float4*)&Ab[(long)(m0 + row) * 1536 + k0 + kc];
    As[(kc + 0) * 68 + row] = v.x; As[(kc + 1) * 68 + row] = v.y;
    As[(kc + 2) * 68 + row] = v.z; As[(kc + 3) * 68 + row] = v.w;
    v = *(const float4*)&Ab[(long)(m0 + row + 32) * 1536 + k0 + kc];
    As[(kc + 0) * 68 + row + 32] = v.x; As[(kc + 1) * 68 + row + 32] = v.y;
    As[(kc + 2) * 68 + row + 32] = v.z; As[(kc + 3) * 68 + row + 32] = v.w;
    v = *(const float4*)&Wb[(long)(n0 + row) * 1536 + k0 + kc];
    Ws[(kc + 0) * 68 + row] = v.x; Ws[(kc + 1) * 68 + row] = v.y;
    Ws[(kc + 2) * 68 + row] = v.z; Ws[(kc + 3) * 68 + row] = v.w;
    v = *(const float4*)&Wb[(long)(n0 + row + 32) * 1536 + k0 + kc];
    Ws[(kc + 0) * 68 + row + 32] = v.x; Ws[(kc + 1) * 68 + row + 32] = v.y;
    Ws[(kc + 2) * 68 + row + 32] = v.z; Ws[(kc + 3) * 68 + row + 32] = v.w;
    __syncthreads();
    for (int kk = 0; kk < 32; ++kk) {
      float4 a = *(const float4*)&As[kk * 68 + tm * 4];
      float4 w = *(const float4*)&Ws[kk * 68 + tn * 4];
      acc[0][0] += a.x * w.x; acc[0][1] += a.x * w.y; acc[0][2] += a.x * w.z; acc[0][3] += a.x * w.w;
      acc[1][0] += a.y * w.x; acc[1][1] += a.y * w.y; acc[1][2] += a.y * w.z; acc[1][3] += a.y * w.w;
      acc[2][0] += a.z * w.x; acc[2][1] += a.z * w.y; acc[2][2] += a.z * w.z; acc[2][3] += a.z * w.w;
      acc[3][0] += a.w * w.x; acc[3][1] += a.w * w.y; acc[3][2] += a.w * w.z; acc[3][3] += a.w * w.w;
    }
    __syncthreads();
  }
#pragma unroll
  for (int mi = 0; mi < 4; ++mi) {
    float4 o;
    o.x = acc[mi][0]; o.y = acc[mi][1]; o.z = acc[mi][2]; o.w = acc[mi][3];
    *(float4*)&C[(long)(m0 + tm * 4 + mi) * 512 + n0 + tn * 4] = o;
  }
}

// ---------------- stage E2: GEMM-2, A = gelu(H0+H1+H2+H3+fb1) fused in staging ----------------
__global__ __launch_bounds__(256) void gemm2_fused(const float* __restrict__ H0,
                                                   const float* __restrict__ H1,
                                                   const float* __restrict__ H2,
                                                   const float* __restrict__ H3,
                                                   const float* __restrict__ fb1,
                                                   const float* __restrict__ W,
                                                   const float* __restrict__ fb2,
                                                   float* __restrict__ C) {
  __shared__ float As[32 * 68];
  __shared__ float Ws[32 * 68];
  int m0 = (blockIdx.x >> 3) * 64, n0 = (blockIdx.x & 7) * 64;
  int tid = threadIdx.x;
  int tm = tid & 15, tn = tid >> 4;
  float acc[4][4];
#pragma unroll
  for (int i = 0; i < 4; ++i)
#pragma unroll
    for (int j = 0; j < 4; ++j) acc[i][j] = 0.f;
  int row = tid >> 3, kc = (tid & 7) * 4;
  for (int k0 = 0; k0 < 512; k0 += 32) {
    float4 bs = *(const float4*)&fb1[k0 + kc];
#pragma unroll
    for (int half = 0; half < 2; ++half) {
      long off = (long)(m0 + row + half * 32) * 512 + k0 + kc;
      float4 h0 = *(const float4*)&H0[off];
      float4 h1 = *(const float4*)&H1[off];
      float4 h2 = *(const float4*)&H2[off];
      float4 h3 = *(const float4*)&H3[off];
      float4 v;
      v.x = h0.x + h1.x + h2.x + h3.x + bs.x;
      v.y = h0.y + h1.y + h2.y + h3.y + bs.y;
      v.z = h0.z + h1.z + h2.z + h3.z + bs.z;
      v.w = h0.w + h1.w + h2.w + h3.w + bs.w;
      v.x = 0.5f * v.x * (1.f + erff(v.x * 0.7071067811865475f));
      v.y = 0.5f * v.y * (1.f + erff(v.y * 0.7071067811865475f));
      v.z = 0.5f * v.z * (1.f + erff(v.z * 0.7071067811865475f));
      v.w = 0.5f * v.w * (1.f + erff(v.w * 0.7071067811865475f));
      int rr = row + half * 32;
      As[(kc + 0) * 68 + rr] = v.x; As[(kc + 1) * 68 + rr] = v.y;
      As[(kc + 2) * 68 + rr] = v.z; As[(kc + 3) * 68 + rr] = v.w;
    }
    float4 wv = *(const float4*)&W[(long)(n0 + row) * 512 + k0 + kc];
    Ws[(kc + 0) * 68 + row] = wv.x; Ws[(kc + 1) * 68 + row] = wv.y;
    Ws[(kc + 2) * 68 + row] = wv.z; Ws[(kc + 3) * 68 + row] = wv.w;
    wv = *(const float4*)&W[(long)(n0 + row + 32) * 512 + k0 + kc];
    Ws[(kc + 0) * 68 + row + 32] = wv.x; Ws[(kc + 1) * 68 + row + 32] = wv.y;
    Ws[(kc + 2) * 68 + row + 32] = wv.z; Ws[(kc + 3) * 68 + row + 32] = wv.w;
    __syncthreads();
    for (int kk = 0; kk < 32; ++kk) {
      float4 a = *(const float4*)&As[kk * 68 + tm * 4];
      float4 w = *(const float4*)&Ws[kk * 68 + tn * 4];
      acc[0][0] += a.x * w.x; acc[0][1] += a.x * w.y; acc[0][2] += a.x * w.z; acc[0][3] += a.x * w.w;
      acc[1][0] += a.y * w.x; acc[1][1] += a.y * w.y; acc[1][2] += a.y * w.z; acc[1][3] += a.y * w.w;
      acc[2][0] += a.z * w.x; acc[2][1] += a.z * w.y; acc[2][2] += a.z * w.z; acc[2][3] += a.z * w.w;
      acc[3][0] += a.w * w.x; acc[3][1] += a.w * w.y; acc[3][2] += a.w * w.z; acc[3][3] += a.w * w.w;
    }
    __syncthreads();
  }
  float b0v = fb2[n0 + tn * 4 + 0], b1v = fb2[n0 + tn * 4 + 1];
  float b2v = fb2[n0 + tn * 4 + 2], b3v = fb2[n0 + tn * 4 + 3];
#pragma unroll
  for (int mi = 0; mi < 4; ++mi) {
    float4 o;
    o.x = acc[mi][0] + b0v; o.y = acc[mi][1] + b1v;
    o.z = acc[mi][2] + b2v; o.w = acc[mi][3] + b3v;
    *(float4*)&C[(long)(m0 + tm * 4 + mi) * 512 + n0 + tn * 4] = o;
  }
}

extern "C" void kernel_launch(void* const* d_in, const int* in_sizes, int n_in,
                              void* d_out, int out_size, void* d_ws, size_t ws_size,
                              hipStream_t stream) {
  const float* x    = (const float*)d_in[0];
  const float* a12  = (const float*)d_in[1];
  const float* a24  = (const float*)d_in[2];
  const float* a48  = (const float*)d_in[3];
  const float* a96  = (const float*)d_in[4];
  const float* sb   = (const float*)d_in[5];
  const float* g1iw = (const float*)d_in[6];
  const float* g1ib = (const float*)d_in[7];
  const float* g1ow = (const float*)d_in[8];
  const float* g1ob = (const float*)d_in[9];
  const float* g1lg = (const float*)d_in[10];
  const float* g1lb = (const float*)d_in[11];
  const float* g2iw = (const float*)d_in[12];
  const float* g2ib = (const float*)d_in[13];
  const float* g2ow = (const float*)d_in[14];
  const float* g2ob = (const float*)d_in[15];
  const float* g2lg = (const float*)d_in[16];
  const float* g2lb = (const float*)d_in[17];
  const float* fw1  = (const float*)d_in[18];
  const float* fb1  = (const float*)d_in[19];
  const float* fw2  = (const float*)d_in[20];
  const float* fb2  = (const float*)d_in[21];

  if (ws_size < (size_t)WS_FLOATS * sizeof(float)) return;

  float* ws   = (float*)d_ws;
  float* xT   = ws + OFF_XT;
  float* avg  = ws + OFF_AVG;
  int*   per  = (int*)(ws + OFF_PER);
  float* mp   = ws + OFF_MP;
  float* atb  = ws + OFF_AT;
  float* waf  = ws + OFF_WAF;
  float* qat  = ws + OFF_QAT;
  float* vat  = ws + OFF_VAT;
  float* ovt  = ws + OFF_OVT;
  float* cons = ws + OFF_CON;
  float* vbuf = ws + OFF_VB;
  float* mtab = ws + OFF_MT;
  float* def  = ws + OFF_DEF;
  float* zc   = ws + OFF_ZC;
  float* comb = ws + OFF_COMB;
  float* hbuf = ws + OFF_H;
  float* hbu2 = ws + OFF_H2;
  float* hbu3 = ws + OFF_ZC;   // zc dead after attn_y
  float* hbu4 = ws + OFF_MP;   // mp low range dead after attn_a (trend reads mp+1634436)
  float* out  = (float*)d_out;

  transpose_kernel<<<192, 256, 0, stream>>>(x, xT);
  acf_kernel<<<Cn * 6, 256, 0, stream>>>(xT, avg);
  periods_kernel<<<32, 256, 0, stream>>>(avg, per);
  build_mpinv_kernel<<<190, 256, 0, stream>>>(per, mp);
  prep1<<<224, 256, 0, stream>>>(a12, a24, a48, a96, g1iw, g1ib, g2iw, g2ib, sb,
                                 atb, cons, vbuf);
  wa_gemm2<<<144, 256, 0, stream>>>(g1iw, g2iw, atb, waf, qat, vat);
  prep2<<<336, 256, 0, stream>>>(g1ow, g1ob, g2ow, g2ob, vbuf, cons,
                                 qat, waf, mtab, def, vat, ovt);
  attn_a<<<512, 256, 0, stream>>>(xT, per, mp, mtab, def, zc);
  attn_y<<<256, 256, 0, stream>>>(per, zc, atb, ovt, cons, sb,
                                  g1lg, g1lb, g2lg, g2lb, comb);
  trend_kernel<<<Cn, 256, 0, stream>>>(xT, mp + 1634436L, atb + 84L * 512, sb, comb);
  gemm1_part<<<1024, 256, 0, stream>>>(comb, fw1, hbuf, hbu2, hbu3, hbu4);
  gemm2_fused<<<256, 256, 0, stream>>>(hbuf, hbu2, hbu3, hbu4, fb1, fw2, fb2, out);
}